// Round 4
// baseline (550.991 us; speedup 1.0000x reference)
//
#include <hip/hip_runtime.h>
#include <hip/hip_bf16.h>
#include <stdint.h>

#define T_TOK 2048
#define NH 16
#define NKV 8
#define HD 128
#define SW 512

typedef _Float16 f16x8 __attribute__((ext_vector_type(8)));
typedef float f32x4 __attribute__((ext_vector_type(4)));

// C[M x ldc] = A (MxK row-major) * B^T; B is NxK row-major fp32, selected from
// {B0,B1,B2} by block-column splits (fused QKV). A is fp32 (A_F32=1) or fp16.
// fp32->fp16 conversion fused into LDS staging; fp32 MFMA accumulate (f16 MFMA:
// 2 extra mantissa bits vs bf16 at the same MFMA rate — the numerics fix).
// Out: fp16 (OUT_F32=0) for intermediates, fp32 for the final output.
template<int A_F32, int OUT_F32>
__global__ __launch_bounds__(256)
void gemm_bt(const void* __restrict__ Av,
             const float* __restrict__ B0,
             const float* __restrict__ B1,
             const float* __restrict__ B2,
             int split1, int split2,
             void* __restrict__ Cv,
             int M, int N, int K, int ldc)
{
    __shared__ __align__(16) _Float16 As[128 * 32];
    __shared__ __align__(16) _Float16 Bs[128 * 32];

    const int tid  = threadIdx.x;
    const int wave = tid >> 6;
    const int lane = tid & 63;
    const int bm = blockIdx.y * 128;
    const int bn = blockIdx.x * 128;
    const int wm = (wave >> 1) * 64;
    const int wn = (wave & 1) * 64;
    const int qd = lane >> 4;           // quad 0..3
    const int md = lane & 15;

    // choose B matrix for this block column (block-uniform)
    const float* Bm;
    int bnb;
    if (bn >= split2)      { Bm = B2; bnb = bn - split2; }
    else if (bn >= split1) { Bm = B1; bnb = bn - split1; }
    else                   { Bm = B0; bnb = bn; }

    f32x4 acc[4][4] = {};

    for (int k0 = 0; k0 < K; k0 += 32) {
        // stage 128x32 A-tile and B-tile as fp16: 512 chunks of 8 elems, 2/thread
        f16x8 ra[2], rb[2];
        #pragma unroll
        for (int c = 0; c < 2; ++c) {
            const int e   = c * 256 + tid;   // chunk id 0..511
            const int row = e >> 2;          // 0..127
            const int col = (e & 3) * 8;     // 0,8,16,24
            if (A_F32) {
                const float* ap = (const float*)Av + (size_t)(bm + row) * K + k0 + col;
                float4 f0 = *(const float4*)ap;
                float4 f1 = *(const float4*)(ap + 4);
                ra[c][0] = (_Float16)f0.x; ra[c][1] = (_Float16)f0.y;
                ra[c][2] = (_Float16)f0.z; ra[c][3] = (_Float16)f0.w;
                ra[c][4] = (_Float16)f1.x; ra[c][5] = (_Float16)f1.y;
                ra[c][6] = (_Float16)f1.z; ra[c][7] = (_Float16)f1.w;
            } else {
                ra[c] = *(const f16x8*)((const _Float16*)Av + (size_t)(bm + row) * K + k0 + col);
            }
            {
                const float* bp = Bm + (size_t)(bnb + row) * K + k0 + col;
                float4 f0 = *(const float4*)bp;
                float4 f1 = *(const float4*)(bp + 4);
                rb[c][0] = (_Float16)f0.x; rb[c][1] = (_Float16)f0.y;
                rb[c][2] = (_Float16)f0.z; rb[c][3] = (_Float16)f0.w;
                rb[c][4] = (_Float16)f1.x; rb[c][5] = (_Float16)f1.y;
                rb[c][6] = (_Float16)f1.z; rb[c][7] = (_Float16)f1.w;
            }
        }
        __syncthreads();
        #pragma unroll
        for (int c = 0; c < 2; ++c) {
            const int e   = c * 256 + tid;
            const int row = e >> 2;
            const int col = (e & 3) * 8;
            *(f16x8*)(&As[row * 32 + col]) = ra[c];
            *(f16x8*)(&Bs[row * 32 + col]) = rb[c];
        }
        __syncthreads();

        f16x8 af[4], bg[4];
        #pragma unroll
        for (int i = 0; i < 4; ++i) {
            af[i] = *(const f16x8*)(&As[(wm + i * 16 + md) * 32 + qd * 8]);
            bg[i] = *(const f16x8*)(&Bs[(wn + i * 16 + md) * 32 + qd * 8]);
        }
        #pragma unroll
        for (int i = 0; i < 4; ++i) {
            #pragma unroll
            for (int j = 0; j < 4; ++j) {
                acc[i][j] = __builtin_amdgcn_mfma_f32_16x16x32_f16(af[i], bg[j], acc[i][j], 0, 0, 0);
            }
        }
    }

    // C/D layout: col = lane&15, row = quad*4 + reg  [verified m89/m91; dtype-independent]
    #pragma unroll
    for (int i = 0; i < 4; ++i) {
        #pragma unroll
        for (int j = 0; j < 4; ++j) {
            #pragma unroll
            for (int r = 0; r < 4; ++r) {
                const int row = bm + wm + i * 16 + qd * 4 + r;
                const int col = bn + wn + j * 16 + md;
                if (OUT_F32) ((float*)Cv)[(size_t)row * ldc + col] = acc[i][j][r];
                else ((_Float16*)Cv)[(size_t)row * ldc + col] = (_Float16)acc[i][j][r];
            }
        }
    }
}

// One wave per head-vector of 128. Lane holds elements (lane, lane+64) so the
// RoPE rotate-half pair lives in one lane. r<16: q head r; r<24: k head r-16;
// else: v head r-24 (offset in qkv row is r*128 in all cases).
__global__ __launch_bounds__(256)
void norm_rope(const _Float16* __restrict__ qkv,   // T x 4096 (fp16)
               const float* __restrict__ cosp,     // T x 128 (fp32)
               const float* __restrict__ sinp,
               const float* __restrict__ qnw,      // 128 (fp32)
               const float* __restrict__ knw,
               _Float16* __restrict__ qo,          // T x 16 x 128
               _Float16* __restrict__ ko,          // T x 8 x 128
               _Float16* __restrict__ vo)          // T x 8 x 128
{
    const int idx  = blockIdx.x * 4 + (threadIdx.x >> 6);
    const int lane = threadIdx.x & 63;
    const int t = idx >> 5;
    const int r = idx & 31;

    const size_t base = (size_t)t * 4096 + r * 128;
    float x0 = (float)qkv[base + lane];
    float x1 = (float)qkv[base + lane + 64];

    float ss = x0 * x0 + x1 * x1;
    #pragma unroll
    for (int s = 32; s; s >>= 1) ss += __shfl_xor(ss, s, 64);
    const float inv = rsqrtf(ss * (1.0f / 128.0f) + 1e-6f);
    float y0 = x0 * inv, y1 = x1 * inv;

    if (r < 16)      { y0 *= qnw[lane]; y1 *= qnw[lane + 64]; }
    else if (r < 24) { y0 *= knw[lane]; y1 *= knw[lane + 64]; }

    if (r < 24) {  // RoPE on q and k only
        const float c0 = cosp[t * 128 + lane];
        const float s0 = sinp[t * 128 + lane];
        const float c1 = cosp[t * 128 + lane + 64];
        const float s1 = sinp[t * 128 + lane + 64];
        const float o0 = y0 * c0 - y1 * s0;
        const float o1 = y1 * c1 + y0 * s1;
        y0 = o0; y1 = o1;
    }

    const _Float16 b0 = (_Float16)y0, b1 = (_Float16)y1;
    if (r < 16)      { _Float16* p = qo + ((size_t)t * NH  + r)        * HD; p[lane] = b0; p[lane + 64] = b1; }
    else if (r < 24) { _Float16* p = ko + ((size_t)t * NKV + (r - 16)) * HD; p[lane] = b0; p[lane + 64] = b1; }
    else             { _Float16* p = vo + ((size_t)t * NKV + (r - 24)) * HD; p[lane] = b0; p[lane + 64] = b1; }
}

// Sliding-window GQA flash attention (VALU, correctness-first).
// Block = (head h, 64-token q-tile). 4 threads per q-row, 32 dims each.
// K/V chunks of 64 keys staged to LDS as fp32 with part-rotation swizzle
// (pos = p*32 + ((j+8p)&31)) so the 4 part-groups hit disjoint banks.
__global__ __launch_bounds__(256)
void attn_sw(const _Float16* __restrict__ q,   // T x 16 x 128
             const _Float16* __restrict__ k,   // T x 8 x 128
             const _Float16* __restrict__ v,   // T x 8 x 128
             const int* __restrict__ cu,       // [0, 1024, 2048]
             _Float16* __restrict__ attn)      // T x (16*128)
{
    __shared__ float Ks[64 * 128];
    __shared__ float Vs[64 * 128];

    const int h    = blockIdx.y;
    const int kvh  = h >> 1;          // n_rep = 2
    const int t0   = blockIdx.x * 64;
    const int tid  = threadIdx.x;
    const int row  = tid >> 2;        // 0..63
    const int part = tid & 3;
    const int t    = t0 + row;

    int seg_lo = cu[0];
    if (t0 >= cu[1]) seg_lo = cu[1];

    // load my q slice (fp32) into registers
    float qreg[32];
    {
        const _Float16* qp = q + ((size_t)t * NH + h) * HD + part * 32;
        #pragma unroll
        for (int b = 0; b < 4; ++b) {
            f16x8 raw = *(const f16x8*)(qp + b * 8);
            #pragma unroll
            for (int j = 0; j < 8; ++j) qreg[b * 8 + j] = (float)raw[j];
        }
    }

    float mrun = -1e30f, lrun = 0.f;
    float o[32];
    #pragma unroll
    for (int j = 0; j < 32; ++j) o[j] = 0.f;

    const int lo_row = (seg_lo > t - (SW - 1)) ? seg_lo : (t - (SW - 1));  // per-row lowest valid key
    const int blk_lo = (seg_lo > t0 - (SW - 1)) ? seg_lo : (t0 - (SW - 1));
    const int c_lo = blk_lo & ~63;

    for (int cs = c_lo; cs <= t0 + 63; cs += 64) {
        __syncthreads();
        // cooperative stage: 64 keys x 128 dims, fp16 -> fp32, swizzled
        #pragma unroll
        for (int g = 0; g < 4; ++g) {
            const int e  = g * 256 + tid;    // 16B-group id, 0..1023
            const int rr = e >> 4;           // key row 0..63
            const int d0 = (e & 15) * 8;     // dim 0..120
            const int p  = d0 >> 5;
            const int j0 = d0 & 31;
            const int dst = rr * 128 + p * 32 + ((j0 + p * 8) & 31);
            const size_t goff = ((size_t)(cs + rr) * NKV + kvh) * HD + d0;
            f16x8 rk = *(const f16x8*)(k + goff);
            f16x8 rv = *(const f16x8*)(v + goff);
            *(float4*)(Ks + dst)     = make_float4((float)rk[0], (float)rk[1], (float)rk[2], (float)rk[3]);
            *(float4*)(Ks + dst + 4) = make_float4((float)rk[4], (float)rk[5], (float)rk[6], (float)rk[7]);
            *(float4*)(Vs + dst)     = make_float4((float)rv[0], (float)rv[1], (float)rv[2], (float)rv[3]);
            *(float4*)(Vs + dst + 4) = make_float4((float)rv[4], (float)rv[5], (float)rv[6], (float)rv[7]);
        }
        __syncthreads();

        const int smax = (63 < t - cs) ? 63 : (t - cs);
        int smin = lo_row - cs; if (smin < 0) smin = 0;

        for (int sl = smin; sl <= smax; ++sl) {
            const float* kr = Ks + sl * 128;
            float sc = 0.f;
            #pragma unroll
            for (int b = 0; b < 4; ++b) {
                const int pos = part * 32 + (((b * 8) + part * 8) & 31);
                float4 ka = *(const float4*)(kr + pos);
                float4 kb = *(const float4*)(kr + pos + 4);
                sc += qreg[b*8+0]*ka.x + qreg[b*8+1]*ka.y + qreg[b*8+2]*ka.z + qreg[b*8+3]*ka.w
                    + qreg[b*8+4]*kb.x + qreg[b*8+5]*kb.y + qreg[b*8+6]*kb.z + qreg[b*8+7]*kb.w;
            }
            // reduce over the 4 parts of this row (lanes differ in bits 0..1)
            sc += __shfl_xor(sc, 1, 64);
            sc += __shfl_xor(sc, 2, 64);

            const float mn = fmaxf(mrun, sc);
            if (mn > mrun) {  // lazy rescale
                const float scale = __expf(mrun - mn);
                lrun *= scale;
                #pragma unroll
                for (int j = 0; j < 32; ++j) o[j] *= scale;
                mrun = mn;
            }
            const float p = __expf(sc - mrun);
            lrun += p;

            const float* vr = Vs + sl * 128;
            #pragma unroll
            for (int b = 0; b < 4; ++b) {
                const int pos = part * 32 + (((b * 8) + part * 8) & 31);
                float4 va = *(const float4*)(vr + pos);
                float4 vb = *(const float4*)(vr + pos + 4);
                o[b*8+0] += p * va.x; o[b*8+1] += p * va.y; o[b*8+2] += p * va.z; o[b*8+3] += p * va.w;
                o[b*8+4] += p * vb.x; o[b*8+5] += p * vb.y; o[b*8+6] += p * vb.z; o[b*8+7] += p * vb.w;
            }
        }
    }

    const float linv = 1.0f / lrun;
    _Float16* op = attn + ((size_t)t * NH + h) * HD + part * 32;
    #pragma unroll
    for (int j = 0; j < 32; ++j) op[j] = (_Float16)(o[j] * linv);
}

extern "C" void kernel_launch(void* const* d_in, const int* in_sizes, int n_in,
                              void* d_out, int out_size, void* d_ws, size_t ws_size,
                              hipStream_t stream)
{
    const float* hs   = (const float*)d_in[0];   // (1,T,2048) fp32
    const float* cosp = (const float*)d_in[1];   // (1,T,128)  fp32
    const float* sinp = (const float*)d_in[2];
    const float* qw   = (const float*)d_in[3];   // (2048,2048)
    const float* kw   = (const float*)d_in[4];   // (1024,2048)
    const float* vw   = (const float*)d_in[5];
    const float* ow   = (const float*)d_in[6];   // (2048,2048)
    const float* qnw  = (const float*)d_in[7];   // (128,)
    const float* knw  = (const float*)d_in[8];
    const int*   cu   = (const int*)d_in[9];
    float*       out  = (float*)d_out;           // (1,T,2048) fp32

    // workspace (fp16): qkv[T,4096] | q[T,16,128] | k[T,8,128] | v[T,8,128];
    // attn output aliases the dead qkv buffer.
    _Float16* qkv   = (_Float16*)d_ws;
    _Float16* qb    = qkv  + (size_t)T_TOK * 4096;
    _Float16* kb    = qb   + (size_t)T_TOK * 2048;
    _Float16* vb    = kb   + (size_t)T_TOK * 1024;
    _Float16* attnb = qkv;   // reuse: qkv is dead after norm_rope

    const dim3 blk(256);

    // fused QKV projection: N = 4096 (q 0..2047 | k 2048..3071 | v 3072..4095)
    gemm_bt<1, 0><<<dim3(32, 16), blk, 0, stream>>>(hs, qw, kw, vw, 2048, 3072,
                                                    qkv, T_TOK, 4096, 2048, 4096);
    norm_rope<<<dim3((T_TOK * 32) / 4), blk, 0, stream>>>(qkv, cosp, sinp, qnw, knw, qb, kb, vb);
    attn_sw<<<dim3(T_TOK / 64, NH), blk, 0, stream>>>(qb, kb, vb, cu, attnb);
    // O projection: A = attn (fp16), B = o_w (fp32), out fp32
    gemm_bt<0, 1><<<dim3(16, 16), blk, 0, stream>>>(attnb, ow, ow, ow, 1 << 30, 1 << 30,
                                                    out, T_TOK, 2048, 2048, 2048);
}

// Round 5
// 307.303 us; speedup vs baseline: 1.7930x; 1.7930x over previous
//
#include <hip/hip_runtime.h>
#include <hip/hip_bf16.h>
#include <stdint.h>

#define T_TOK 2048
#define NH 16
#define NKV 8
#define HD 128
#define SW 512

typedef _Float16 f16x8 __attribute__((ext_vector_type(8)));
typedef _Float16 f16x4 __attribute__((ext_vector_type(4)));
typedef float f32x4 __attribute__((ext_vector_type(4)));

// C[M x ldc] = A (MxK row-major) * B^T; B is NxK row-major fp32, selected from
// {B0,B1,B2} by block-column splits (fused QKV). A is fp32 (A_F32=1) or fp16.
template<int A_F32, int OUT_F32>
__global__ __launch_bounds__(256)
void gemm_bt(const void* __restrict__ Av,
             const float* __restrict__ B0,
             const float* __restrict__ B1,
             const float* __restrict__ B2,
             int split1, int split2,
             void* __restrict__ Cv,
             int M, int N, int K, int ldc)
{
    __shared__ __align__(16) _Float16 As[128 * 32];
    __shared__ __align__(16) _Float16 Bs[128 * 32];

    const int tid  = threadIdx.x;
    const int wave = tid >> 6;
    const int lane = tid & 63;
    const int bm = blockIdx.y * 128;
    const int bn = blockIdx.x * 128;
    const int wm = (wave >> 1) * 64;
    const int wn = (wave & 1) * 64;
    const int qd = lane >> 4;
    const int md = lane & 15;

    const float* Bm;
    int bnb;
    if (bn >= split2)      { Bm = B2; bnb = bn - split2; }
    else if (bn >= split1) { Bm = B1; bnb = bn - split1; }
    else                   { Bm = B0; bnb = bn; }

    f32x4 acc[4][4] = {};

    for (int k0 = 0; k0 < K; k0 += 32) {
        f16x8 ra[2], rb[2];
        #pragma unroll
        for (int c = 0; c < 2; ++c) {
            const int e   = c * 256 + tid;
            const int row = e >> 2;
            const int col = (e & 3) * 8;
            if (A_F32) {
                const float* ap = (const float*)Av + (size_t)(bm + row) * K + k0 + col;
                float4 f0 = *(const float4*)ap;
                float4 f1 = *(const float4*)(ap + 4);
                ra[c][0] = (_Float16)f0.x; ra[c][1] = (_Float16)f0.y;
                ra[c][2] = (_Float16)f0.z; ra[c][3] = (_Float16)f0.w;
                ra[c][4] = (_Float16)f1.x; ra[c][5] = (_Float16)f1.y;
                ra[c][6] = (_Float16)f1.z; ra[c][7] = (_Float16)f1.w;
            } else {
                ra[c] = *(const f16x8*)((const _Float16*)Av + (size_t)(bm + row) * K + k0 + col);
            }
            {
                const float* bp = Bm + (size_t)(bnb + row) * K + k0 + col;
                float4 f0 = *(const float4*)bp;
                float4 f1 = *(const float4*)(bp + 4);
                rb[c][0] = (_Float16)f0.x; rb[c][1] = (_Float16)f0.y;
                rb[c][2] = (_Float16)f0.z; rb[c][3] = (_Float16)f0.w;
                rb[c][4] = (_Float16)f1.x; rb[c][5] = (_Float16)f1.y;
                rb[c][6] = (_Float16)f1.z; rb[c][7] = (_Float16)f1.w;
            }
        }
        __syncthreads();
        #pragma unroll
        for (int c = 0; c < 2; ++c) {
            const int e   = c * 256 + tid;
            const int row = e >> 2;
            const int col = (e & 3) * 8;
            *(f16x8*)(&As[row * 32 + col]) = ra[c];
            *(f16x8*)(&Bs[row * 32 + col]) = rb[c];
        }
        __syncthreads();

        f16x8 af[4], bg[4];
        #pragma unroll
        for (int i = 0; i < 4; ++i) {
            af[i] = *(const f16x8*)(&As[(wm + i * 16 + md) * 32 + qd * 8]);
            bg[i] = *(const f16x8*)(&Bs[(wn + i * 16 + md) * 32 + qd * 8]);
        }
        #pragma unroll
        for (int i = 0; i < 4; ++i) {
            #pragma unroll
            for (int j = 0; j < 4; ++j) {
                acc[i][j] = __builtin_amdgcn_mfma_f32_16x16x32_f16(af[i], bg[j], acc[i][j], 0, 0, 0);
            }
        }
    }

    #pragma unroll
    for (int i = 0; i < 4; ++i) {
        #pragma unroll
        for (int j = 0; j < 4; ++j) {
            #pragma unroll
            for (int r = 0; r < 4; ++r) {
                const int row = bm + wm + i * 16 + qd * 4 + r;
                const int col = bn + wn + j * 16 + md;
                if (OUT_F32) ((float*)Cv)[(size_t)row * ldc + col] = acc[i][j][r];
                else ((_Float16*)Cv)[(size_t)row * ldc + col] = (_Float16)acc[i][j][r];
            }
        }
    }
}

// RMSNorm + RoPE for q (r<16) and k (16<=r<24) head-vectors only.
__global__ __launch_bounds__(256)
void norm_rope(const _Float16* __restrict__ qkv,   // T x 4096 (fp16)
               const float* __restrict__ cosp,     // T x 128 (fp32)
               const float* __restrict__ sinp,
               const float* __restrict__ qnw,
               const float* __restrict__ knw,
               _Float16* __restrict__ qo,          // T x 16 x 128
               _Float16* __restrict__ ko)          // T x 8 x 128
{
    const unsigned idx  = blockIdx.x * 4 + (threadIdx.x >> 6);
    const int lane = threadIdx.x & 63;
    const int t = idx / 24;
    const int r = idx - t * 24;

    const size_t base = (size_t)t * 4096 + r * 128;
    float x0 = (float)qkv[base + lane];
    float x1 = (float)qkv[base + lane + 64];

    float ss = x0 * x0 + x1 * x1;
    #pragma unroll
    for (int s = 32; s; s >>= 1) ss += __shfl_xor(ss, s, 64);
    const float inv = rsqrtf(ss * (1.0f / 128.0f) + 1e-6f);
    float y0 = x0 * inv, y1 = x1 * inv;

    if (r < 16) { y0 *= qnw[lane]; y1 *= qnw[lane + 64]; }
    else        { y0 *= knw[lane]; y1 *= knw[lane + 64]; }

    const float c0 = cosp[t * 128 + lane];
    const float s0 = sinp[t * 128 + lane];
    const float c1 = cosp[t * 128 + lane + 64];
    const float s1 = sinp[t * 128 + lane + 64];
    const float o0 = y0 * c0 - y1 * s0;
    const float o1 = y1 * c1 + y0 * s1;

    const _Float16 b0 = (_Float16)o0, b1 = (_Float16)o1;
    if (r < 16) { _Float16* p = qo + ((size_t)t * NH  + r)        * HD; p[lane] = b0; p[lane + 64] = b1; }
    else        { _Float16* p = ko + ((size_t)t * NKV + (r - 16)) * HD; p[lane] = b0; p[lane + 64] = b1; }
}

// RMSNorm (no weight) for v + global transpose to vt[kvh][d][t] so attention
// can stage V^T with coalesced 16B loads. Block = (64-token tile, kv-head).
__global__ __launch_bounds__(256)
void norm_v(const _Float16* __restrict__ qkv,   // T x 4096; v at col 3072
            _Float16* __restrict__ vt)          // KV x 128 x T
{
    __shared__ _Float16 tile[128 * 72];  // [d][tok], pad 72

    const int t0  = blockIdx.x * 64;
    const int kvh = blockIdx.y;
    const int tid = threadIdx.x;
    const int tok = tid >> 2;         // 0..63
    const int part = tid & 3;         // 32 dims each

    const _Float16* vp = qkv + (size_t)(t0 + tok) * 4096 + 3072 + kvh * 128 + part * 32;
    f16x8 raw[4];
    float x[32];
    float ss = 0.f;
    #pragma unroll
    for (int b = 0; b < 4; ++b) {
        raw[b] = *(const f16x8*)(vp + b * 8);
        #pragma unroll
        for (int j = 0; j < 8; ++j) { x[b*8+j] = (float)raw[b][j]; ss += x[b*8+j] * x[b*8+j]; }
    }
    ss += __shfl_xor(ss, 1, 64);
    ss += __shfl_xor(ss, 2, 64);
    const float inv = rsqrtf(ss * (1.0f / 128.0f) + 1e-6f);
    #pragma unroll
    for (int j = 0; j < 32; ++j) tile[(part * 32 + j) * 72 + tok] = (_Float16)(x[j] * inv);
    __syncthreads();

    // coalesced writeout: thread owns (d = tid>>1, half = tid&1) -> 32 tokens
    const int d = tid >> 1, half = tid & 1;
    _Float16* op = vt + ((size_t)kvh * HD + d) * T_TOK + t0 + half * 32;
    #pragma unroll
    for (int j = 0; j < 4; ++j)
        *(f16x8*)(op + j * 8) = *(const f16x8*)(&tile[d * 72 + half * 32 + j * 8]);
}

// MFMA sliding-window GQA flash attention.
// Block = (64-token q-tile, head); 4 waves, each owns 16 q-rows.
// Per 64-key chunk: S=QK^T (MFMA) -> mask -> online softmax (C-layout) ->
// P^T via LDS -> PV (MFMA, B=V^T). Chunk keys provably within segment
// (cu entries are 64-aligned), so mask = causal + window only.
__global__ __launch_bounds__(256)
void attn_mfma(const _Float16* __restrict__ q,   // T x 16 x 128
               const _Float16* __restrict__ k,   // T x 8 x 128
               const _Float16* __restrict__ vt,  // KV x 128 x T
               const int* __restrict__ cu,
               _Float16* __restrict__ attn)      // T x (16*128)
{
    __shared__ __align__(16) _Float16 Ks[64 * 136];   // [key][dim] pad 136
    __shared__ __align__(16) _Float16 Vs[128 * 72];   // [dim][key] pad 72
    __shared__ __align__(16) _Float16 Ps[64 * 72];    // [key][q]   pad 72

    const int h   = blockIdx.y;
    const int kvh = h >> 1;
    const int t0  = blockIdx.x * 64;
    const int tid = threadIdx.x;
    const int w   = tid >> 6;
    const int lane = tid & 63;
    const int qd  = lane >> 4;        // quad 0..3
    const int md  = lane & 15;

    int seg_lo = (t0 >= cu[1]) ? cu[1] : cu[0];

    // Q fragments: A[m=md][kdim = ks*32 + qd*8 + j]
    f16x8 qf[4];
    {
        const _Float16* qp = q + ((size_t)(t0 + w * 16 + md) * NH + h) * HD;
        #pragma unroll
        for (int ks = 0; ks < 4; ++ks) qf[ks] = *(const f16x8*)(qp + ks * 32 + qd * 8);
    }

    f32x4 O[8] = {};
    float mR[4], lR[4];
    #pragma unroll
    for (int r = 0; r < 4; ++r) { mR[r] = -1e30f; lR[r] = 0.f; }

    int blk_lo = t0 - (SW - 1); if (blk_lo < seg_lo) blk_lo = seg_lo;
    const int c_lo = blk_lo & ~63;

    for (int cs = c_lo; cs <= t0 + 63; cs += 64) {
        __syncthreads();
        #pragma unroll
        for (int g = 0; g < 4; ++g) {   // stage K: 64x128
            const int e = g * 256 + tid;
            const int key = e >> 4, d0 = (e & 15) * 8;
            *(f16x8*)(&Ks[key * 136 + d0]) =
                *(const f16x8*)(k + ((size_t)(cs + key) * NKV + kvh) * HD + d0);
        }
        #pragma unroll
        for (int g = 0; g < 4; ++g) {   // stage V^T: 128x64
            const int e = g * 256 + tid;
            const int d = e >> 3, c0 = (e & 7) * 8;
            *(f16x8*)(&Vs[d * 72 + c0]) =
                *(const f16x8*)(vt + ((size_t)kvh * HD + d) * T_TOK + cs + c0);
        }
        __syncthreads();

        // S = Q K^T : 4 n-tiles of 16 keys
        f32x4 S[4] = {};
        #pragma unroll
        for (int nt = 0; nt < 4; ++nt) {
            #pragma unroll
            for (int ks = 0; ks < 4; ++ks) {
                f16x8 kf = *(const f16x8*)(&Ks[(nt * 16 + md) * 136 + ks * 32 + qd * 8]);
                S[nt] = __builtin_amdgcn_mfma_f32_16x16x32_f16(qf[ks], kf, S[nt], 0, 0, 0);
            }
        }

        // mask + row stats (row = qd*4 + r within wave's 16-row strip)
        const int rowb = t0 + w * 16 + qd * 4;
        float alpha[4];
        #pragma unroll
        for (int r = 0; r < 4; ++r) {
            const int rt = rowb + r;
            float mx = -1e30f;
            #pragma unroll
            for (int nt = 0; nt < 4; ++nt) {
                const int col = cs + nt * 16 + md;
                const bool ok = (col <= rt) && (col + (SW - 1) >= rt);
                const float s = ok ? S[nt][r] : -1e30f;
                S[nt][r] = s;
                mx = fmaxf(mx, s);
            }
            mx = fmaxf(mx, __shfl_xor(mx, 1, 64));
            mx = fmaxf(mx, __shfl_xor(mx, 2, 64));
            mx = fmaxf(mx, __shfl_xor(mx, 4, 64));
            mx = fmaxf(mx, __shfl_xor(mx, 8, 64));
            const float mn = fmaxf(mR[r], mx);
            alpha[r] = __expf(mR[r] - mn);
            mR[r] = mn;
        }

        // P = exp(S - m), row sums, write P^T to LDS (b64: 4 rows per write)
        #pragma unroll
        for (int r = 0; r < 4; ++r) {
            float rs = 0.f;
            #pragma unroll
            for (int nt = 0; nt < 4; ++nt) {
                const float p = __expf(S[nt][r] - mR[r]);
                S[nt][r] = p;
                rs += p;
            }
            rs += __shfl_xor(rs, 1, 64);
            rs += __shfl_xor(rs, 2, 64);
            rs += __shfl_xor(rs, 4, 64);
            rs += __shfl_xor(rs, 8, 64);
            lR[r] = lR[r] * alpha[r] + rs;
        }
        #pragma unroll
        for (int nt = 0; nt < 4; ++nt) {
            f16x4 p4;
            #pragma unroll
            for (int r = 0; r < 4; ++r) p4[r] = (_Float16)S[nt][r];
            *(f16x4*)(&Ps[(nt * 16 + md) * 72 + w * 16 + qd * 4]) = p4;
        }

        // rescale O, then PV accumulate
        #pragma unroll
        for (int nt = 0; nt < 8; ++nt)
            #pragma unroll
            for (int r = 0; r < 4; ++r) O[nt][r] *= alpha[r];

        #pragma unroll
        for (int ks2 = 0; ks2 < 2; ++ks2) {
            f16x8 pf;   // A[m=md][kkey = ks2*32 + qd*8 + j] = Ps[key][w*16+md]
            #pragma unroll
            for (int j = 0; j < 8; ++j)
                pf[j] = Ps[(ks2 * 32 + qd * 8 + j) * 72 + w * 16 + md];
            #pragma unroll
            for (int nt = 0; nt < 8; ++nt) {
                f16x8 vf = *(const f16x8*)(&Vs[(nt * 16 + md) * 72 + ks2 * 32 + qd * 8]);
                O[nt] = __builtin_amdgcn_mfma_f32_16x16x32_f16(pf, vf, O[nt], 0, 0, 0);
            }
        }
    }

    // epilogue: O/l -> LDS (reuse Ks) -> coalesced global write
    float inv[4];
    #pragma unroll
    for (int r = 0; r < 4; ++r) inv[r] = 1.0f / lR[r];
    __syncthreads();
    #pragma unroll
    for (int nt = 0; nt < 8; ++nt)
        #pragma unroll
        for (int r = 0; r < 4; ++r)
            Ks[(w * 16 + qd * 4 + r) * 136 + nt * 16 + md] = (_Float16)(O[nt][r] * inv[r]);
    __syncthreads();
    #pragma unroll
    for (int g = 0; g < 4; ++g) {
        const int e = g * 256 + tid;
        const int row = e >> 4, d0 = (e & 15) * 8;
        *(f16x8*)(attn + ((size_t)(t0 + row) * NH + h) * HD + d0) =
            *(const f16x8*)(&Ks[row * 136 + d0]);
    }
}

extern "C" void kernel_launch(void* const* d_in, const int* in_sizes, int n_in,
                              void* d_out, int out_size, void* d_ws, size_t ws_size,
                              hipStream_t stream)
{
    const float* hs   = (const float*)d_in[0];
    const float* cosp = (const float*)d_in[1];
    const float* sinp = (const float*)d_in[2];
    const float* qw   = (const float*)d_in[3];
    const float* kw   = (const float*)d_in[4];
    const float* vw   = (const float*)d_in[5];
    const float* ow   = (const float*)d_in[6];
    const float* qnw  = (const float*)d_in[7];
    const float* knw  = (const float*)d_in[8];
    const int*   cu   = (const int*)d_in[9];
    float*       out  = (float*)d_out;

    // workspace (fp16): qkv[T,4096] | q[T,16,128] | k[T,8,128] | vt[KV,128,T]
    _Float16* qkv   = (_Float16*)d_ws;
    _Float16* qb    = qkv  + (size_t)T_TOK * 4096;
    _Float16* kb    = qb   + (size_t)T_TOK * 2048;
    _Float16* vtb   = kb   + (size_t)T_TOK * 1024;
    _Float16* attnb = qkv;   // qkv dead after norm kernels

    const dim3 blk(256);

    gemm_bt<1, 0><<<dim3(32, 16), blk, 0, stream>>>(hs, qw, kw, vw, 2048, 3072,
                                                    qkv, T_TOK, 4096, 2048, 4096);
    norm_rope<<<dim3((T_TOK * 24) / 4), blk, 0, stream>>>(qkv, cosp, sinp, qnw, knw, qb, kb);
    norm_v<<<dim3(T_TOK / 64, NKV), blk, 0, stream>>>(qkv, vtb);
    attn_mfma<<<dim3(T_TOK / 64, NH), blk, 0, stream>>>(qb, kb, vtb, cu, attnb);
    gemm_bt<0, 1><<<dim3(16, 16), blk, 0, stream>>>(attnb, ow, ow, ow, 1 << 30, 1 << 30,
                                                    out, T_TOK, 2048, 2048, 2048);
}

// Round 6
// 275.561 us; speedup vs baseline: 1.9995x; 1.1152x over previous
//
#include <hip/hip_runtime.h>
#include <hip/hip_bf16.h>
#include <stdint.h>

#define T_TOK 2048
#define NH 16
#define NKV 8
#define HD 128
#define SW 512

typedef _Float16 f16x8 __attribute__((ext_vector_type(8)));
typedef _Float16 f16x4 __attribute__((ext_vector_type(4)));
typedef float f32x4 __attribute__((ext_vector_type(4)));

#define LDP 40   // LDS row stride (fp16): 20 words, gcd(20,32)=4 -> uniform banks

// n multiple of 2048*8; fp32 -> fp16 vectorized cast
__global__ __launch_bounds__(256)
void cast_f16(const float* __restrict__ src, _Float16* __restrict__ dst, int n)
{
    const int i = (blockIdx.x * 256 + threadIdx.x) * 8;
    if (i >= n) return;
    float4 f0 = *(const float4*)(src + i);
    float4 f1 = *(const float4*)(src + i + 4);
    f16x8 o;
    o[0] = (_Float16)f0.x; o[1] = (_Float16)f0.y; o[2] = (_Float16)f0.z; o[3] = (_Float16)f0.w;
    o[4] = (_Float16)f1.x; o[5] = (_Float16)f1.y; o[6] = (_Float16)f1.z; o[7] = (_Float16)f1.w;
    *(f16x8*)(dst + i) = o;
}

// C[M x ldc] = A (MxK row-major) * B^T; B is NxK row-major, selected from
// {B0,B1,B2} by block-column splits (fused QKV). LDS rows padded to 40 fp16:
// bank-census is exactly 8 accesses/bank for staging writes AND fragment
// reads (conflict-free), vs 8-way aliasing at stride 32.
template<int A_F16, int B_F16, int OUT_F32>
__global__ __launch_bounds__(256)
void gemm_bt(const void* __restrict__ Av,
             const void* __restrict__ B0,
             const void* __restrict__ B1,
             const void* __restrict__ B2,
             int split1, int split2,
             void* __restrict__ Cv,
             int M, int N, int K, int ldc)
{
    __shared__ __align__(16) _Float16 As[128 * LDP];
    __shared__ __align__(16) _Float16 Bs[128 * LDP];

    const int tid  = threadIdx.x;
    const int wave = tid >> 6;
    const int lane = tid & 63;
    const int bm = blockIdx.y * 128;
    const int bn = blockIdx.x * 128;
    const int wm = (wave >> 1) * 64;
    const int wn = (wave & 1) * 64;
    const int qd = lane >> 4;
    const int md = lane & 15;

    const void* Bm;
    int bnb;
    if (bn >= split2)      { Bm = B2; bnb = bn - split2; }
    else if (bn >= split1) { Bm = B1; bnb = bn - split1; }
    else                   { Bm = B0; bnb = bn; }

    f32x4 acc[4][4] = {};

    for (int k0 = 0; k0 < K; k0 += 32) {
        f16x8 ra[2], rb[2];
        #pragma unroll
        for (int c = 0; c < 2; ++c) {
            const int e   = c * 256 + tid;
            const int row = e >> 2;
            const int col = (e & 3) * 8;
            if (A_F16) {
                ra[c] = *(const f16x8*)((const _Float16*)Av + (size_t)(bm + row) * K + k0 + col);
            } else {
                const float* ap = (const float*)Av + (size_t)(bm + row) * K + k0 + col;
                float4 f0 = *(const float4*)ap;
                float4 f1 = *(const float4*)(ap + 4);
                ra[c][0] = (_Float16)f0.x; ra[c][1] = (_Float16)f0.y;
                ra[c][2] = (_Float16)f0.z; ra[c][3] = (_Float16)f0.w;
                ra[c][4] = (_Float16)f1.x; ra[c][5] = (_Float16)f1.y;
                ra[c][6] = (_Float16)f1.z; ra[c][7] = (_Float16)f1.w;
            }
            if (B_F16) {
                rb[c] = *(const f16x8*)((const _Float16*)Bm + (size_t)(bnb + row) * K + k0 + col);
            } else {
                const float* bp = (const float*)Bm + (size_t)(bnb + row) * K + k0 + col;
                float4 f0 = *(const float4*)bp;
                float4 f1 = *(const float4*)(bp + 4);
                rb[c][0] = (_Float16)f0.x; rb[c][1] = (_Float16)f0.y;
                rb[c][2] = (_Float16)f0.z; rb[c][3] = (_Float16)f0.w;
                rb[c][4] = (_Float16)f1.x; rb[c][5] = (_Float16)f1.y;
                rb[c][6] = (_Float16)f1.z; rb[c][7] = (_Float16)f1.w;
            }
        }
        __syncthreads();
        #pragma unroll
        for (int c = 0; c < 2; ++c) {
            const int e   = c * 256 + tid;
            const int row = e >> 2;
            const int col = (e & 3) * 8;
            *(f16x8*)(&As[row * LDP + col]) = ra[c];
            *(f16x8*)(&Bs[row * LDP + col]) = rb[c];
        }
        __syncthreads();

        f16x8 af[4], bg[4];
        #pragma unroll
        for (int i = 0; i < 4; ++i) {
            af[i] = *(const f16x8*)(&As[(wm + i * 16 + md) * LDP + qd * 8]);
            bg[i] = *(const f16x8*)(&Bs[(wn + i * 16 + md) * LDP + qd * 8]);
        }
        #pragma unroll
        for (int i = 0; i < 4; ++i) {
            #pragma unroll
            for (int j = 0; j < 4; ++j) {
                acc[i][j] = __builtin_amdgcn_mfma_f32_16x16x32_f16(af[i], bg[j], acc[i][j], 0, 0, 0);
            }
        }
    }

    // C/D layout: col = lane&15, row = quad*4 + reg  [verified m89/m91]
    #pragma unroll
    for (int i = 0; i < 4; ++i) {
        #pragma unroll
        for (int j = 0; j < 4; ++j) {
            #pragma unroll
            for (int r = 0; r < 4; ++r) {
                const int row = bm + wm + i * 16 + qd * 4 + r;
                const int col = bn + wn + j * 16 + md;
                if (OUT_F32) ((float*)Cv)[(size_t)row * ldc + col] = acc[i][j][r];
                else ((_Float16*)Cv)[(size_t)row * ldc + col] = (_Float16)acc[i][j][r];
            }
        }
    }
}

// RMSNorm + RoPE for q (r<16) and k (16<=r<24) head-vectors only.
__global__ __launch_bounds__(256)
void norm_rope(const _Float16* __restrict__ qkv,   // T x 4096 (fp16)
               const float* __restrict__ cosp,     // T x 128 (fp32)
               const float* __restrict__ sinp,
               const float* __restrict__ qnw,
               const float* __restrict__ knw,
               _Float16* __restrict__ qo,          // T x 16 x 128
               _Float16* __restrict__ ko)          // T x 8 x 128
{
    const unsigned idx  = blockIdx.x * 4 + (threadIdx.x >> 6);
    const int lane = threadIdx.x & 63;
    const int t = idx / 24;
    const int r = idx - t * 24;

    const size_t base = (size_t)t * 4096 + r * 128;
    float x0 = (float)qkv[base + lane];
    float x1 = (float)qkv[base + lane + 64];

    float ss = x0 * x0 + x1 * x1;
    #pragma unroll
    for (int s = 32; s; s >>= 1) ss += __shfl_xor(ss, s, 64);
    const float inv = rsqrtf(ss * (1.0f / 128.0f) + 1e-6f);
    float y0 = x0 * inv, y1 = x1 * inv;

    if (r < 16) { y0 *= qnw[lane]; y1 *= qnw[lane + 64]; }
    else        { y0 *= knw[lane]; y1 *= knw[lane + 64]; }

    const float c0 = cosp[t * 128 + lane];
    const float s0 = sinp[t * 128 + lane];
    const float c1 = cosp[t * 128 + lane + 64];
    const float s1 = sinp[t * 128 + lane + 64];
    const float o0 = y0 * c0 - y1 * s0;
    const float o1 = y1 * c1 + y0 * s1;

    const _Float16 b0 = (_Float16)o0, b1 = (_Float16)o1;
    if (r < 16) { _Float16* p = qo + ((size_t)t * NH  + r)        * HD; p[lane] = b0; p[lane + 64] = b1; }
    else        { _Float16* p = ko + ((size_t)t * NKV + (r - 16)) * HD; p[lane] = b0; p[lane + 64] = b1; }
}

// RMSNorm (no weight) for v + global transpose to vt[kvh][d][t].
__global__ __launch_bounds__(256)
void norm_v(const _Float16* __restrict__ qkv,   // T x 4096; v at col 3072
            _Float16* __restrict__ vt)          // KV x 128 x T
{
    __shared__ _Float16 tile[128 * 72];

    const int t0  = blockIdx.x * 64;
    const int kvh = blockIdx.y;
    const int tid = threadIdx.x;
    const int tok = tid >> 2;
    const int part = tid & 3;

    const _Float16* vp = qkv + (size_t)(t0 + tok) * 4096 + 3072 + kvh * 128 + part * 32;
    f16x8 raw[4];
    float x[32];
    float ss = 0.f;
    #pragma unroll
    for (int b = 0; b < 4; ++b) {
        raw[b] = *(const f16x8*)(vp + b * 8);
        #pragma unroll
        for (int j = 0; j < 8; ++j) { x[b*8+j] = (float)raw[b][j]; ss += x[b*8+j] * x[b*8+j]; }
    }
    ss += __shfl_xor(ss, 1, 64);
    ss += __shfl_xor(ss, 2, 64);
    const float inv = rsqrtf(ss * (1.0f / 128.0f) + 1e-6f);
    #pragma unroll
    for (int j = 0; j < 32; ++j) tile[(part * 32 + j) * 72 + tok] = (_Float16)(x[j] * inv);
    __syncthreads();

    const int d = tid >> 1, half = tid & 1;
    _Float16* op = vt + ((size_t)kvh * HD + d) * T_TOK + t0 + half * 32;
    #pragma unroll
    for (int j = 0; j < 4; ++j)
        *(f16x8*)(op + j * 8) = *(const f16x8*)(&tile[d * 72 + half * 32 + j * 8]);
}

// MFMA sliding-window GQA flash attention (unchanged from round 5).
__global__ __launch_bounds__(256)
void attn_mfma(const _Float16* __restrict__ q,   // T x 16 x 128
               const _Float16* __restrict__ k,   // T x 8 x 128
               const _Float16* __restrict__ vt,  // KV x 128 x T
               const int* __restrict__ cu,
               _Float16* __restrict__ attn)      // T x (16*128)
{
    __shared__ __align__(16) _Float16 Ks[64 * 136];
    __shared__ __align__(16) _Float16 Vs[128 * 72];
    __shared__ __align__(16) _Float16 Ps[64 * 72];

    const int h   = blockIdx.y;
    const int kvh = h >> 1;
    const int t0  = blockIdx.x * 64;
    const int tid = threadIdx.x;
    const int w   = tid >> 6;
    const int lane = tid & 63;
    const int qd  = lane >> 4;
    const int md  = lane & 15;

    int seg_lo = (t0 >= cu[1]) ? cu[1] : cu[0];

    f16x8 qf[4];
    {
        const _Float16* qp = q + ((size_t)(t0 + w * 16 + md) * NH + h) * HD;
        #pragma unroll
        for (int ks = 0; ks < 4; ++ks) qf[ks] = *(const f16x8*)(qp + ks * 32 + qd * 8);
    }

    f32x4 O[8] = {};
    float mR[4], lR[4];
    #pragma unroll
    for (int r = 0; r < 4; ++r) { mR[r] = -1e30f; lR[r] = 0.f; }

    int blk_lo = t0 - (SW - 1); if (blk_lo < seg_lo) blk_lo = seg_lo;
    const int c_lo = blk_lo & ~63;

    for (int cs = c_lo; cs <= t0 + 63; cs += 64) {
        __syncthreads();
        #pragma unroll
        for (int g = 0; g < 4; ++g) {
            const int e = g * 256 + tid;
            const int key = e >> 4, d0 = (e & 15) * 8;
            *(f16x8*)(&Ks[key * 136 + d0]) =
                *(const f16x8*)(k + ((size_t)(cs + key) * NKV + kvh) * HD + d0);
        }
        #pragma unroll
        for (int g = 0; g < 4; ++g) {
            const int e = g * 256 + tid;
            const int d = e >> 3, c0 = (e & 7) * 8;
            *(f16x8*)(&Vs[d * 72 + c0]) =
                *(const f16x8*)(vt + ((size_t)kvh * HD + d) * T_TOK + cs + c0);
        }
        __syncthreads();

        f32x4 S[4] = {};
        #pragma unroll
        for (int nt = 0; nt < 4; ++nt) {
            #pragma unroll
            for (int ks = 0; ks < 4; ++ks) {
                f16x8 kf = *(const f16x8*)(&Ks[(nt * 16 + md) * 136 + ks * 32 + qd * 8]);
                S[nt] = __builtin_amdgcn_mfma_f32_16x16x32_f16(qf[ks], kf, S[nt], 0, 0, 0);
            }
        }

        const int rowb = t0 + w * 16 + qd * 4;
        float alpha[4];
        #pragma unroll
        for (int r = 0; r < 4; ++r) {
            const int rt = rowb + r;
            float mx = -1e30f;
            #pragma unroll
            for (int nt = 0; nt < 4; ++nt) {
                const int col = cs + nt * 16 + md;
                const bool ok = (col <= rt) && (col + (SW - 1) >= rt);
                const float s = ok ? S[nt][r] : -1e30f;
                S[nt][r] = s;
                mx = fmaxf(mx, s);
            }
            mx = fmaxf(mx, __shfl_xor(mx, 1, 64));
            mx = fmaxf(mx, __shfl_xor(mx, 2, 64));
            mx = fmaxf(mx, __shfl_xor(mx, 4, 64));
            mx = fmaxf(mx, __shfl_xor(mx, 8, 64));
            const float mn = fmaxf(mR[r], mx);
            alpha[r] = __expf(mR[r] - mn);
            mR[r] = mn;
        }

        #pragma unroll
        for (int r = 0; r < 4; ++r) {
            float rs = 0.f;
            #pragma unroll
            for (int nt = 0; nt < 4; ++nt) {
                const float p = __expf(S[nt][r] - mR[r]);
                S[nt][r] = p;
                rs += p;
            }
            rs += __shfl_xor(rs, 1, 64);
            rs += __shfl_xor(rs, 2, 64);
            rs += __shfl_xor(rs, 4, 64);
            rs += __shfl_xor(rs, 8, 64);
            lR[r] = lR[r] * alpha[r] + rs;
        }
        #pragma unroll
        for (int nt = 0; nt < 4; ++nt) {
            f16x4 p4;
            #pragma unroll
            for (int r = 0; r < 4; ++r) p4[r] = (_Float16)S[nt][r];
            *(f16x4*)(&Ps[(nt * 16 + md) * 72 + w * 16 + qd * 4]) = p4;
        }

        #pragma unroll
        for (int nt = 0; nt < 8; ++nt)
            #pragma unroll
            for (int r = 0; r < 4; ++r) O[nt][r] *= alpha[r];

        #pragma unroll
        for (int ks2 = 0; ks2 < 2; ++ks2) {
            f16x8 pf;
            #pragma unroll
            for (int j = 0; j < 8; ++j)
                pf[j] = Ps[(ks2 * 32 + qd * 8 + j) * 72 + w * 16 + md];
            #pragma unroll
            for (int nt = 0; nt < 8; ++nt) {
                f16x8 vf = *(const f16x8*)(&Vs[(nt * 16 + md) * 72 + ks2 * 32 + qd * 8]);
                O[nt] = __builtin_amdgcn_mfma_f32_16x16x32_f16(pf, vf, O[nt], 0, 0, 0);
            }
        }
    }

    float inv[4];
    #pragma unroll
    for (int r = 0; r < 4; ++r) inv[r] = 1.0f / lR[r];
    __syncthreads();
    #pragma unroll
    for (int nt = 0; nt < 8; ++nt)
        #pragma unroll
        for (int r = 0; r < 4; ++r)
            Ks[(w * 16 + qd * 4 + r) * 136 + nt * 16 + md] = (_Float16)(O[nt][r] * inv[r]);
    __syncthreads();
    #pragma unroll
    for (int g = 0; g < 4; ++g) {
        const int e = g * 256 + tid;
        const int row = e >> 4, d0 = (e & 15) * 8;
        *(f16x8*)(attn + ((size_t)(t0 + row) * NH + h) * HD + d0) =
            *(const f16x8*)(&Ks[row * 136 + d0]);
    }
}

extern "C" void kernel_launch(void* const* d_in, const int* in_sizes, int n_in,
                              void* d_out, int out_size, void* d_ws, size_t ws_size,
                              hipStream_t stream)
{
    const float* hs   = (const float*)d_in[0];
    const float* cosp = (const float*)d_in[1];
    const float* sinp = (const float*)d_in[2];
    const float* qw   = (const float*)d_in[3];
    const float* kw   = (const float*)d_in[4];
    const float* vw   = (const float*)d_in[5];
    const float* ow   = (const float*)d_in[6];
    const float* qnw  = (const float*)d_in[7];
    const float* knw  = (const float*)d_in[8];
    const int*   cu   = (const int*)d_in[9];
    float*       out  = (float*)d_out;

    // base workspace (fp16): qkv[T,4096] | q[T,16,128] | k[T,8,128] | vt[KV,128,T]
    _Float16* qkv   = (_Float16*)d_ws;
    _Float16* qb    = qkv  + (size_t)T_TOK * 4096;
    _Float16* kb    = qb   + (size_t)T_TOK * 2048;
    _Float16* vtb   = kb   + (size_t)T_TOK * 1024;
    _Float16* attnb = qkv;   // qkv dead after norm kernels

    // optional fp16 pre-cast region (needs 64 MiB total ws)
    _Float16* hs16  = vtb  + (size_t)T_TOK * 1024;
    _Float16* qw16  = hs16 + (size_t)T_TOK * 2048;
    _Float16* kw16  = qw16 + (size_t)2048 * 2048;
    _Float16* vw16  = kw16 + (size_t)1024 * 2048;
    _Float16* ow16  = vw16 + (size_t)1024 * 2048;
    const size_t need = ((size_t)T_TOK * 4096 + T_TOK * 2048 + T_TOK * 1024 + T_TOK * 1024
                       + T_TOK * 2048 + 2048 * 2048 + 1024 * 2048 + 1024 * 2048 + 2048 * 2048)
                       * sizeof(_Float16);
    const bool precast = ws_size >= need;   // ws_size is call-invariant: graph-safe

    const dim3 blk(256);

    if (precast) {
        cast_f16<<<2048, blk, 0, stream>>>(hs, hs16, T_TOK * 2048);
        cast_f16<<<2048, blk, 0, stream>>>(qw, qw16, 2048 * 2048);
        cast_f16<<<1024, blk, 0, stream>>>(kw, kw16, 1024 * 2048);
        cast_f16<<<1024, blk, 0, stream>>>(vw, vw16, 1024 * 2048);
        cast_f16<<<2048, blk, 0, stream>>>(ow, ow16, 2048 * 2048);
        gemm_bt<1, 1, 0><<<dim3(32, 16), blk, 0, stream>>>(hs16, qw16, kw16, vw16, 2048, 3072,
                                                           qkv, T_TOK, 4096, 2048, 4096);
    } else {
        gemm_bt<0, 0, 0><<<dim3(32, 16), blk, 0, stream>>>(hs, qw, kw, vw, 2048, 3072,
                                                           qkv, T_TOK, 4096, 2048, 4096);
    }
    norm_rope<<<dim3((T_TOK * 24) / 4), blk, 0, stream>>>(qkv, cosp, sinp, qnw, knw, qb, kb);
    norm_v<<<dim3(T_TOK / 64, NKV), blk, 0, stream>>>(qkv, vtb);
    attn_mfma<<<dim3(T_TOK / 64, NH), blk, 0, stream>>>(qb, kb, vtb, cu, attnb);
    if (precast) {
        gemm_bt<1, 1, 1><<<dim3(16, 16), blk, 0, stream>>>(attnb, ow16, ow16, ow16, 1 << 30, 1 << 30,
                                                           out, T_TOK, 2048, 2048, 2048);
    } else {
        gemm_bt<1, 0, 1><<<dim3(16, 16), blk, 0, stream>>>(attnb, ow, ow, ow, 1 << 30, 1 << 30,
                                                           out, T_TOK, 2048, 2048, 2048);
    }
}

// Round 7
// 266.414 us; speedup vs baseline: 2.0682x; 1.0343x over previous
//
#include <hip/hip_runtime.h>
#include <hip/hip_bf16.h>
#include <stdint.h>

#define T_TOK 2048
#define NH 16
#define NKV 8
#define HD 128
#define SW 512

typedef _Float16 f16x8 __attribute__((ext_vector_type(8)));
typedef _Float16 f16x4 __attribute__((ext_vector_type(4)));
typedef float f32x4 __attribute__((ext_vector_type(4)));

#define AS1 __attribute__((address_space(1)))
#define AS3 __attribute__((address_space(3)))

// One kernel casts all five fp32 tensors to fp16 (block-uniform branch).
// Ranges (2048 elems/block): hs[0,2048) qw[2048,4096) kw[4096,5120)
// vw[5120,6144) ow[6144,8192).
__global__ __launch_bounds__(256)
void cast_all(const float* __restrict__ hs, const float* __restrict__ qw,
              const float* __restrict__ kw, const float* __restrict__ vw,
              const float* __restrict__ ow,
              _Float16* __restrict__ hs16, _Float16* __restrict__ qw16,
              _Float16* __restrict__ kw16, _Float16* __restrict__ vw16,
              _Float16* __restrict__ ow16)
{
    const int b = blockIdx.x;
    const float* src; _Float16* dst; int base;
    if (b < 2048)      { src = hs; dst = hs16; base = b; }
    else if (b < 4096) { src = qw; dst = qw16; base = b - 2048; }
    else if (b < 5120) { src = kw; dst = kw16; base = b - 4096; }
    else if (b < 6144) { src = vw; dst = vw16; base = b - 5120; }
    else               { src = ow; dst = ow16; base = b - 6144; }
    const int i = (base * 256 + threadIdx.x) * 8;
    float4 f0 = *(const float4*)(src + i);
    float4 f1 = *(const float4*)(src + i + 4);
    f16x8 o;
    o[0] = (_Float16)f0.x; o[1] = (_Float16)f0.y; o[2] = (_Float16)f0.z; o[3] = (_Float16)f0.w;
    o[4] = (_Float16)f1.x; o[5] = (_Float16)f1.y; o[6] = (_Float16)f1.z; o[7] = (_Float16)f1.w;
    *(f16x8*)(dst + i) = o;
}

// m97-structure GEMM: C = A * B^T, fp16 in, fp32 acc. Staging via
// global_load_lds width=16 (direct HBM->LDS DMA, no VGPR round-trip).
// LDS unpadded stride 32 (DMA dest is wave-uniform base + lane*16 --
// padding is illegal). Fragment-read bank conflicts accepted (m98: the
// 874 TF reference kernel runs with them).
template<int OUT_F32>
__global__ __launch_bounds__(256)
void gemm_dma(const _Float16* __restrict__ A,
              const _Float16* __restrict__ B0,
              const _Float16* __restrict__ B1,
              const _Float16* __restrict__ B2,
              int split1, int split2,
              void* __restrict__ Cv,
              int K, int ldc)
{
    __shared__ __align__(16) _Float16 As[128 * 32];
    __shared__ __align__(16) _Float16 Bs[128 * 32];

    const int tid  = threadIdx.x;
    const int wave = tid >> 6;
    const int lane = tid & 63;
    const int bm = blockIdx.y * 128;
    const int bn = blockIdx.x * 128;
    const int wm = (wave >> 1) * 64;
    const int wn = (wave & 1) * 64;
    const int qd = lane >> 4;
    const int md = lane & 15;
    const int srow = lane >> 2;        // staging row within 16-row chunk
    const int scol = (lane & 3) * 8;   // staging col (8 fp16 = 16 B)

    const _Float16* Bm;
    int bnb;
    if (bn >= split2)      { Bm = B2; bnb = bn - split2; }
    else if (bn >= split1) { Bm = B1; bnb = bn - split1; }
    else                   { Bm = B0; bnb = bn; }

    f32x4 acc[4][4] = {};

    for (int k0 = 0; k0 < K; k0 += 32) {
        __syncthreads();
        #pragma unroll
        for (int c = 0; c < 2; ++c) {
            const int chunk = wave * 2 + c;    // 0..7: 16 rows each
            const _Float16* ga = A  + (size_t)(bm  + chunk * 16 + srow) * K + k0 + scol;
            const _Float16* gb = Bm + (size_t)(bnb + chunk * 16 + srow) * K + k0 + scol;
            __builtin_amdgcn_global_load_lds((const AS1 void*)ga, (AS3 void*)(&As[chunk * 512]), 16, 0, 0);
            __builtin_amdgcn_global_load_lds((const AS1 void*)gb, (AS3 void*)(&Bs[chunk * 512]), 16, 0, 0);
        }
        __syncthreads();   // vmcnt(0) drain + barrier: DMA results visible

        f16x8 af[4], bg[4];
        #pragma unroll
        for (int i = 0; i < 4; ++i) {
            af[i] = *(const f16x8*)(&As[(wm + i * 16 + md) * 32 + qd * 8]);
            bg[i] = *(const f16x8*)(&Bs[(wn + i * 16 + md) * 32 + qd * 8]);
        }
        #pragma unroll
        for (int i = 0; i < 4; ++i) {
            #pragma unroll
            for (int j = 0; j < 4; ++j) {
                acc[i][j] = __builtin_amdgcn_mfma_f32_16x16x32_f16(af[i], bg[j], acc[i][j], 0, 0, 0);
            }
        }
    }

    // C/D layout: col = lane&15, row = quad*4 + reg  [verified m89/m91]
    #pragma unroll
    for (int i = 0; i < 4; ++i) {
        #pragma unroll
        for (int j = 0; j < 4; ++j) {
            #pragma unroll
            for (int r = 0; r < 4; ++r) {
                const int row = bm + wm + i * 16 + qd * 4 + r;
                const int col = bn + wn + j * 16 + md;
                if (OUT_F32) ((float*)Cv)[(size_t)row * ldc + col] = acc[i][j][r];
                else ((_Float16*)Cv)[(size_t)row * ldc + col] = (_Float16)acc[i][j][r];
            }
        }
    }
}

// Fallback GEMM (register staging, fp32 operands) for small-ws path only.
template<int A_F16, int OUT_F32>
__global__ __launch_bounds__(256)
void gemm_bt(const void* __restrict__ Av,
             const float* __restrict__ B0,
             const float* __restrict__ B1,
             const float* __restrict__ B2,
             int split1, int split2,
             void* __restrict__ Cv,
             int K, int ldc)
{
    __shared__ __align__(16) _Float16 As[128 * 40];
    __shared__ __align__(16) _Float16 Bs[128 * 40];

    const int tid  = threadIdx.x;
    const int wave = tid >> 6;
    const int lane = tid & 63;
    const int bm = blockIdx.y * 128;
    const int bn = blockIdx.x * 128;
    const int wm = (wave >> 1) * 64;
    const int wn = (wave & 1) * 64;
    const int qd = lane >> 4;
    const int md = lane & 15;

    const float* Bm;
    int bnb;
    if (bn >= split2)      { Bm = B2; bnb = bn - split2; }
    else if (bn >= split1) { Bm = B1; bnb = bn - split1; }
    else                   { Bm = B0; bnb = bn; }

    f32x4 acc[4][4] = {};

    for (int k0 = 0; k0 < K; k0 += 32) {
        f16x8 ra[2], rb[2];
        #pragma unroll
        for (int c = 0; c < 2; ++c) {
            const int e   = c * 256 + tid;
            const int row = e >> 2;
            const int col = (e & 3) * 8;
            if (A_F16) {
                ra[c] = *(const f16x8*)((const _Float16*)Av + (size_t)(bm + row) * K + k0 + col);
            } else {
                const float* ap = (const float*)Av + (size_t)(bm + row) * K + k0 + col;
                float4 f0 = *(const float4*)ap;
                float4 f1 = *(const float4*)(ap + 4);
                ra[c][0] = (_Float16)f0.x; ra[c][1] = (_Float16)f0.y;
                ra[c][2] = (_Float16)f0.z; ra[c][3] = (_Float16)f0.w;
                ra[c][4] = (_Float16)f1.x; ra[c][5] = (_Float16)f1.y;
                ra[c][6] = (_Float16)f1.z; ra[c][7] = (_Float16)f1.w;
            }
            {
                const float* bp = Bm + (size_t)(bnb + row) * K + k0 + col;
                float4 f0 = *(const float4*)bp;
                float4 f1 = *(const float4*)(bp + 4);
                rb[c][0] = (_Float16)f0.x; rb[c][1] = (_Float16)f0.y;
                rb[c][2] = (_Float16)f0.z; rb[c][3] = (_Float16)f0.w;
                rb[c][4] = (_Float16)f1.x; rb[c][5] = (_Float16)f1.y;
                rb[c][6] = (_Float16)f1.z; rb[c][7] = (_Float16)f1.w;
            }
        }
        __syncthreads();
        #pragma unroll
        for (int c = 0; c < 2; ++c) {
            const int e   = c * 256 + tid;
            const int row = e >> 2;
            const int col = (e & 3) * 8;
            *(f16x8*)(&As[row * 40 + col]) = ra[c];
            *(f16x8*)(&Bs[row * 40 + col]) = rb[c];
        }
        __syncthreads();

        f16x8 af[4], bg[4];
        #pragma unroll
        for (int i = 0; i < 4; ++i) {
            af[i] = *(const f16x8*)(&As[(wm + i * 16 + md) * 40 + qd * 8]);
            bg[i] = *(const f16x8*)(&Bs[(wn + i * 16 + md) * 40 + qd * 8]);
        }
        #pragma unroll
        for (int i = 0; i < 4; ++i) {
            #pragma unroll
            for (int j = 0; j < 4; ++j) {
                acc[i][j] = __builtin_amdgcn_mfma_f32_16x16x32_f16(af[i], bg[j], acc[i][j], 0, 0, 0);
            }
        }
    }

    #pragma unroll
    for (int i = 0; i < 4; ++i) {
        #pragma unroll
        for (int j = 0; j < 4; ++j) {
            #pragma unroll
            for (int r = 0; r < 4; ++r) {
                const int row = bm + wm + i * 16 + qd * 4 + r;
                const int col = bn + wn + j * 16 + md;
                if (OUT_F32) ((float*)Cv)[(size_t)row * ldc + col] = acc[i][j][r];
                else ((_Float16*)Cv)[(size_t)row * ldc + col] = (_Float16)acc[i][j][r];
            }
        }
    }
}

// RMSNorm + RoPE for q (r<16) and k (16<=r<24) head-vectors only.
__global__ __launch_bounds__(256)
void norm_rope(const _Float16* __restrict__ qkv,   // T x 4096 (fp16)
               const float* __restrict__ cosp,     // T x 128 (fp32)
               const float* __restrict__ sinp,
               const float* __restrict__ qnw,
               const float* __restrict__ knw,
               _Float16* __restrict__ qo,          // T x 16 x 128
               _Float16* __restrict__ ko)          // T x 8 x 128
{
    const unsigned idx  = blockIdx.x * 4 + (threadIdx.x >> 6);
    const int lane = threadIdx.x & 63;
    const int t = idx / 24;
    const int r = idx - t * 24;

    const size_t base = (size_t)t * 4096 + r * 128;
    float x0 = (float)qkv[base + lane];
    float x1 = (float)qkv[base + lane + 64];

    float ss = x0 * x0 + x1 * x1;
    #pragma unroll
    for (int s = 32; s; s >>= 1) ss += __shfl_xor(ss, s, 64);
    const float inv = rsqrtf(ss * (1.0f / 128.0f) + 1e-6f);
    float y0 = x0 * inv, y1 = x1 * inv;

    if (r < 16) { y0 *= qnw[lane]; y1 *= qnw[lane + 64]; }
    else        { y0 *= knw[lane]; y1 *= knw[lane + 64]; }

    const float c0 = cosp[t * 128 + lane];
    const float s0 = sinp[t * 128 + lane];
    const float c1 = cosp[t * 128 + lane + 64];
    const float s1 = sinp[t * 128 + lane + 64];
    const float o0 = y0 * c0 - y1 * s0;
    const float o1 = y1 * c1 + y0 * s1;

    const _Float16 b0 = (_Float16)o0, b1 = (_Float16)o1;
    if (r < 16) { _Float16* p = qo + ((size_t)t * NH  + r)        * HD; p[lane] = b0; p[lane + 64] = b1; }
    else        { _Float16* p = ko + ((size_t)t * NKV + (r - 16)) * HD; p[lane] = b0; p[lane + 64] = b1; }
}

// RMSNorm (no weight) for v + global transpose to vt[kvh][d][t].
__global__ __launch_bounds__(256)
void norm_v(const _Float16* __restrict__ qkv,   // T x 4096; v at col 3072
            _Float16* __restrict__ vt)          // KV x 128 x T
{
    __shared__ _Float16 tile[128 * 72];

    const int t0  = blockIdx.x * 64;
    const int kvh = blockIdx.y;
    const int tid = threadIdx.x;
    const int tok = tid >> 2;
    const int part = tid & 3;

    const _Float16* vp = qkv + (size_t)(t0 + tok) * 4096 + 3072 + kvh * 128 + part * 32;
    f16x8 raw[4];
    float x[32];
    float ss = 0.f;
    #pragma unroll
    for (int b = 0; b < 4; ++b) {
        raw[b] = *(const f16x8*)(vp + b * 8);
        #pragma unroll
        for (int j = 0; j < 8; ++j) { x[b*8+j] = (float)raw[b][j]; ss += x[b*8+j] * x[b*8+j]; }
    }
    ss += __shfl_xor(ss, 1, 64);
    ss += __shfl_xor(ss, 2, 64);
    const float inv = rsqrtf(ss * (1.0f / 128.0f) + 1e-6f);
    #pragma unroll
    for (int j = 0; j < 32; ++j) tile[(part * 32 + j) * 72 + tok] = (_Float16)(x[j] * inv);
    __syncthreads();

    const int d = tid >> 1, half = tid & 1;
    _Float16* op = vt + ((size_t)kvh * HD + d) * T_TOK + t0 + half * 32;
    #pragma unroll
    for (int j = 0; j < 4; ++j)
        *(f16x8*)(op + j * 8) = *(const f16x8*)(&tile[d * 72 + half * 32 + j * 8]);
}

// MFMA sliding-window GQA flash attention (unchanged).
__global__ __launch_bounds__(256)
void attn_mfma(const _Float16* __restrict__ q,   // T x 16 x 128
               const _Float16* __restrict__ k,   // T x 8 x 128
               const _Float16* __restrict__ vt,  // KV x 128 x T
               const int* __restrict__ cu,
               _Float16* __restrict__ attn)      // T x (16*128)
{
    __shared__ __align__(16) _Float16 Ks[64 * 136];
    __shared__ __align__(16) _Float16 Vs[128 * 72];
    __shared__ __align__(16) _Float16 Ps[64 * 72];

    const int h   = blockIdx.y;
    const int kvh = h >> 1;
    const int t0  = blockIdx.x * 64;
    const int tid = threadIdx.x;
    const int w   = tid >> 6;
    const int lane = tid & 63;
    const int qd  = lane >> 4;
    const int md  = lane & 15;

    int seg_lo = (t0 >= cu[1]) ? cu[1] : cu[0];

    f16x8 qf[4];
    {
        const _Float16* qp = q + ((size_t)(t0 + w * 16 + md) * NH + h) * HD;
        #pragma unroll
        for (int ks = 0; ks < 4; ++ks) qf[ks] = *(const f16x8*)(qp + ks * 32 + qd * 8);
    }

    f32x4 O[8] = {};
    float mR[4], lR[4];
    #pragma unroll
    for (int r = 0; r < 4; ++r) { mR[r] = -1e30f; lR[r] = 0.f; }

    int blk_lo = t0 - (SW - 1); if (blk_lo < seg_lo) blk_lo = seg_lo;
    const int c_lo = blk_lo & ~63;

    for (int cs = c_lo; cs <= t0 + 63; cs += 64) {
        __syncthreads();
        #pragma unroll
        for (int g = 0; g < 4; ++g) {
            const int e = g * 256 + tid;
            const int key = e >> 4, d0 = (e & 15) * 8;
            *(f16x8*)(&Ks[key * 136 + d0]) =
                *(const f16x8*)(k + ((size_t)(cs + key) * NKV + kvh) * HD + d0);
        }
        #pragma unroll
        for (int g = 0; g < 4; ++g) {
            const int e = g * 256 + tid;
            const int d = e >> 3, c0 = (e & 7) * 8;
            *(f16x8*)(&Vs[d * 72 + c0]) =
                *(const f16x8*)(vt + ((size_t)kvh * HD + d) * T_TOK + cs + c0);
        }
        __syncthreads();

        f32x4 S[4] = {};
        #pragma unroll
        for (int nt = 0; nt < 4; ++nt) {
            #pragma unroll
            for (int ks = 0; ks < 4; ++ks) {
                f16x8 kf = *(const f16x8*)(&Ks[(nt * 16 + md) * 136 + ks * 32 + qd * 8]);
                S[nt] = __builtin_amdgcn_mfma_f32_16x16x32_f16(qf[ks], kf, S[nt], 0, 0, 0);
            }
        }

        const int rowb = t0 + w * 16 + qd * 4;
        float alpha[4];
        #pragma unroll
        for (int r = 0; r < 4; ++r) {
            const int rt = rowb + r;
            float mx = -1e30f;
            #pragma unroll
            for (int nt = 0; nt < 4; ++nt) {
                const int col = cs + nt * 16 + md;
                const bool ok = (col <= rt) && (col + (SW - 1) >= rt);
                const float s = ok ? S[nt][r] : -1e30f;
                S[nt][r] = s;
                mx = fmaxf(mx, s);
            }
            mx = fmaxf(mx, __shfl_xor(mx, 1, 64));
            mx = fmaxf(mx, __shfl_xor(mx, 2, 64));
            mx = fmaxf(mx, __shfl_xor(mx, 4, 64));
            mx = fmaxf(mx, __shfl_xor(mx, 8, 64));
            const float mn = fmaxf(mR[r], mx);
            alpha[r] = __expf(mR[r] - mn);
            mR[r] = mn;
        }

        #pragma unroll
        for (int r = 0; r < 4; ++r) {
            float rs = 0.f;
            #pragma unroll
            for (int nt = 0; nt < 4; ++nt) {
                const float p = __expf(S[nt][r] - mR[r]);
                S[nt][r] = p;
                rs += p;
            }
            rs += __shfl_xor(rs, 1, 64);
            rs += __shfl_xor(rs, 2, 64);
            rs += __shfl_xor(rs, 4, 64);
            rs += __shfl_xor(rs, 8, 64);
            lR[r] = lR[r] * alpha[r] + rs;
        }
        #pragma unroll
        for (int nt = 0; nt < 4; ++nt) {
            f16x4 p4;
            #pragma unroll
            for (int r = 0; r < 4; ++r) p4[r] = (_Float16)S[nt][r];
            *(f16x4*)(&Ps[(nt * 16 + md) * 72 + w * 16 + qd * 4]) = p4;
        }

        #pragma unroll
        for (int nt = 0; nt < 8; ++nt)
            #pragma unroll
            for (int r = 0; r < 4; ++r) O[nt][r] *= alpha[r];

        #pragma unroll
        for (int ks2 = 0; ks2 < 2; ++ks2) {
            f16x8 pf;
            #pragma unroll
            for (int j = 0; j < 8; ++j)
                pf[j] = Ps[(ks2 * 32 + qd * 8 + j) * 72 + w * 16 + md];
            #pragma unroll
            for (int nt = 0; nt < 8; ++nt) {
                f16x8 vf = *(const f16x8*)(&Vs[(nt * 16 + md) * 72 + ks2 * 32 + qd * 8]);
                O[nt] = __builtin_amdgcn_mfma_f32_16x16x32_f16(pf, vf, O[nt], 0, 0, 0);
            }
        }
    }

    float inv[4];
    #pragma unroll
    for (int r = 0; r < 4; ++r) inv[r] = 1.0f / lR[r];
    __syncthreads();
    #pragma unroll
    for (int nt = 0; nt < 8; ++nt)
        #pragma unroll
        for (int r = 0; r < 4; ++r)
            Ks[(w * 16 + qd * 4 + r) * 136 + nt * 16 + md] = (_Float16)(O[nt][r] * inv[r]);
    __syncthreads();
    #pragma unroll
    for (int g = 0; g < 4; ++g) {
        const int e = g * 256 + tid;
        const int row = e >> 4, d0 = (e & 15) * 8;
        *(f16x8*)(attn + ((size_t)(t0 + row) * NH + h) * HD + d0) =
            *(const f16x8*)(&Ks[row * 136 + d0]);
    }
}

extern "C" void kernel_launch(void* const* d_in, const int* in_sizes, int n_in,
                              void* d_out, int out_size, void* d_ws, size_t ws_size,
                              hipStream_t stream)
{
    const float* hs   = (const float*)d_in[0];
    const float* cosp = (const float*)d_in[1];
    const float* sinp = (const float*)d_in[2];
    const float* qw   = (const float*)d_in[3];
    const float* kw   = (const float*)d_in[4];
    const float* vw   = (const float*)d_in[5];
    const float* ow   = (const float*)d_in[6];
    const float* qnw  = (const float*)d_in[7];
    const float* knw  = (const float*)d_in[8];
    const int*   cu   = (const int*)d_in[9];
    float*       out  = (float*)d_out;

    // base workspace (fp16): qkv[T,4096] | q[T,16,128] | k[T,8,128] | vt[KV,128,T]
    _Float16* qkv   = (_Float16*)d_ws;
    _Float16* qb    = qkv  + (size_t)T_TOK * 4096;
    _Float16* kb    = qb   + (size_t)T_TOK * 2048;
    _Float16* vtb   = kb   + (size_t)T_TOK * 1024;
    _Float16* attnb = qkv;   // qkv dead after norm kernels

    // fp16 pre-cast region (needs ~64 MiB total ws)
    _Float16* hs16  = vtb  + (size_t)T_TOK * 1024;
    _Float16* qw16  = hs16 + (size_t)T_TOK * 2048;
    _Float16* kw16  = qw16 + (size_t)2048 * 2048;
    _Float16* vw16  = kw16 + (size_t)1024 * 2048;
    _Float16* ow16  = vw16 + (size_t)1024 * 2048;
    const size_t need = ((size_t)T_TOK * 4096 + T_TOK * 2048 + T_TOK * 1024 + T_TOK * 1024
                       + T_TOK * 2048 + 2048 * 2048 + 1024 * 2048 + 1024 * 2048 + 2048 * 2048)
                       * sizeof(_Float16);
    const bool precast = ws_size >= need;   // ws_size is call-invariant: graph-safe

    const dim3 blk(256);

    if (precast) {
        cast_all<<<8192, blk, 0, stream>>>(hs, qw, kw, vw, ow, hs16, qw16, kw16, vw16, ow16);
        gemm_dma<0><<<dim3(32, 16), blk, 0, stream>>>(hs16, qw16, kw16, vw16, 2048, 3072,
                                                      qkv, 2048, 4096);
    } else {
        gemm_bt<0, 0><<<dim3(32, 16), blk, 0, stream>>>(hs, qw, kw, vw, 2048, 3072,
                                                        qkv, 2048, 4096);
    }
    norm_rope<<<dim3((T_TOK * 24) / 4), blk, 0, stream>>>(qkv, cosp, sinp, qnw, knw, qb, kb);
    norm_v<<<dim3(T_TOK / 64, NKV), blk, 0, stream>>>(qkv, vtb);
    attn_mfma<<<dim3(T_TOK / 64, NH), blk, 0, stream>>>(qb, kb, vtb, cu, attnb);
    if (precast) {
        gemm_dma<1><<<dim3(16, 16), blk, 0, stream>>>(attnb, ow16, ow16, ow16, 1 << 30, 1 << 30,
                                                      out, 2048, 2048);
    } else {
        gemm_bt<1, 1><<<dim3(16, 16), blk, 0, stream>>>(attnb, ow, ow, ow, 1 << 30, 1 << 30,
                                                        out, 2048, 2048);
    }
}

// Round 8
// 254.132 us; speedup vs baseline: 2.1681x; 1.0483x over previous
//
#include <hip/hip_runtime.h>
#include <hip/hip_bf16.h>
#include <stdint.h>

#define T_TOK 2048
#define NH 16
#define NKV 8
#define HD 128
#define SW 512

typedef _Float16 f16x8 __attribute__((ext_vector_type(8)));
typedef _Float16 f16x4 __attribute__((ext_vector_type(4)));
typedef float f32x4 __attribute__((ext_vector_type(4)));

#define AS1 __attribute__((address_space(1)))
#define AS3 __attribute__((address_space(3)))

// One kernel casts all five fp32 tensors to fp16 (block-uniform branch).
__global__ __launch_bounds__(256)
void cast_all(const float* __restrict__ hs, const float* __restrict__ qw,
              const float* __restrict__ kw, const float* __restrict__ vw,
              const float* __restrict__ ow,
              _Float16* __restrict__ hs16, _Float16* __restrict__ qw16,
              _Float16* __restrict__ kw16, _Float16* __restrict__ vw16,
              _Float16* __restrict__ ow16)
{
    const int b = blockIdx.x;
    const float* src; _Float16* dst; int base;
    if (b < 2048)      { src = hs; dst = hs16; base = b; }
    else if (b < 4096) { src = qw; dst = qw16; base = b - 2048; }
    else if (b < 5120) { src = kw; dst = kw16; base = b - 4096; }
    else if (b < 6144) { src = vw; dst = vw16; base = b - 5120; }
    else               { src = ow; dst = ow16; base = b - 6144; }
    const int i = (base * 256 + threadIdx.x) * 8;
    float4 f0 = *(const float4*)(src + i);
    float4 f1 = *(const float4*)(src + i + 4);
    f16x8 o;
    o[0] = (_Float16)f0.x; o[1] = (_Float16)f0.y; o[2] = (_Float16)f0.z; o[3] = (_Float16)f0.w;
    o[4] = (_Float16)f1.x; o[5] = (_Float16)f1.y; o[6] = (_Float16)f1.z; o[7] = (_Float16)f1.w;
    *(f16x8*)(dst + i) = o;
}

// Double-buffered DMA GEMM: C = A * B^T, fp16 in, fp32 acc.
// Per iter: issue global_load_lds for tile k+1 into buf^1, compute tile k
// from buf, ONE barrier. The vmcnt(0) drain before s_barrier then waits on
// a prefetch that overlapped the whole compute phase — targets the 1-2
// blocks/CU regime where implicit TLP can't hide the drain (O-proj: 1/CU).
template<int OUT_F32>
__global__ __launch_bounds__(256)
void gemm_dma(const _Float16* __restrict__ A,
              const _Float16* __restrict__ B0,
              const _Float16* __restrict__ B1,
              const _Float16* __restrict__ B2,
              int split1, int split2,
              void* __restrict__ Cv,
              int K, int ldc)
{
    __shared__ __align__(16) _Float16 As[2][128 * 32];
    __shared__ __align__(16) _Float16 Bs[2][128 * 32];

    const int tid  = threadIdx.x;
    const int wave = tid >> 6;
    const int lane = tid & 63;
    const int bm = blockIdx.y * 128;
    const int bn = blockIdx.x * 128;
    const int wm = (wave >> 1) * 64;
    const int wn = (wave & 1) * 64;
    const int qd = lane >> 4;
    const int md = lane & 15;
    const int srow = lane >> 2;        // staging row within 16-row chunk
    const int scol = (lane & 3) * 8;   // staging col (8 fp16 = 16 B)

    const _Float16* Bm;
    int bnb;
    if (bn >= split2)      { Bm = B2; bnb = bn - split2; }
    else if (bn >= split1) { Bm = B1; bnb = bn - split1; }
    else                   { Bm = B0; bnb = bn; }

    f32x4 acc[4][4] = {};

    const _Float16* aBase = A  + (size_t)(bm  + wave * 32 + srow) * K + scol;
    const _Float16* bBase = Bm + (size_t)(bnb + wave * 32 + srow) * K + scol;

    const int nIter = K / 32;
    // prologue: stage tile 0 into buf 0
    #pragma unroll
    for (int c = 0; c < 2; ++c) {
        const int chunk = wave * 2 + c;
        __builtin_amdgcn_global_load_lds((const AS1 void*)(aBase + (size_t)c * 16 * K),
                                         (AS3 void*)(&As[0][chunk * 512]), 16, 0, 0);
        __builtin_amdgcn_global_load_lds((const AS1 void*)(bBase + (size_t)c * 16 * K),
                                         (AS3 void*)(&Bs[0][chunk * 512]), 16, 0, 0);
    }
    __syncthreads();

    for (int it = 0; it < nIter; ++it) {
        const int buf = it & 1;
        if (it + 1 < nIter) {
            const int k1 = (it + 1) * 32;
            #pragma unroll
            for (int c = 0; c < 2; ++c) {
                const int chunk = wave * 2 + c;
                __builtin_amdgcn_global_load_lds((const AS1 void*)(aBase + (size_t)c * 16 * K + k1),
                                                 (AS3 void*)(&As[buf ^ 1][chunk * 512]), 16, 0, 0);
                __builtin_amdgcn_global_load_lds((const AS1 void*)(bBase + (size_t)c * 16 * K + k1),
                                                 (AS3 void*)(&Bs[buf ^ 1][chunk * 512]), 16, 0, 0);
            }
        }

        f16x8 af[4], bg[4];
        #pragma unroll
        for (int i = 0; i < 4; ++i) {
            af[i] = *(const f16x8*)(&As[buf][(wm + i * 16 + md) * 32 + qd * 8]);
            bg[i] = *(const f16x8*)(&Bs[buf][(wn + i * 16 + md) * 32 + qd * 8]);
        }
        #pragma unroll
        for (int i = 0; i < 4; ++i) {
            #pragma unroll
            for (int j = 0; j < 4; ++j) {
                acc[i][j] = __builtin_amdgcn_mfma_f32_16x16x32_f16(af[i], bg[j], acc[i][j], 0, 0, 0);
            }
        }
        __syncthreads();   // readers done with buf (next DMA overwrites it) + prefetch drained
    }

    // C/D layout: col = lane&15, row = quad*4 + reg  [verified m89/m91]
    #pragma unroll
    for (int i = 0; i < 4; ++i) {
        #pragma unroll
        for (int j = 0; j < 4; ++j) {
            #pragma unroll
            for (int r = 0; r < 4; ++r) {
                const int row = bm + wm + i * 16 + qd * 4 + r;
                const int col = bn + wn + j * 16 + md;
                if (OUT_F32) ((float*)Cv)[(size_t)row * ldc + col] = acc[i][j][r];
                else ((_Float16*)Cv)[(size_t)row * ldc + col] = (_Float16)acc[i][j][r];
            }
        }
    }
}

// Fallback GEMM (register staging, fp32 operands) for small-ws path only.
template<int A_F16, int OUT_F32>
__global__ __launch_bounds__(256)
void gemm_bt(const void* __restrict__ Av,
             const float* __restrict__ B0,
             const float* __restrict__ B1,
             const float* __restrict__ B2,
             int split1, int split2,
             void* __restrict__ Cv,
             int K, int ldc)
{
    __shared__ __align__(16) _Float16 As[128 * 40];
    __shared__ __align__(16) _Float16 Bs[128 * 40];

    const int tid  = threadIdx.x;
    const int wave = tid >> 6;
    const int lane = tid & 63;
    const int bm = blockIdx.y * 128;
    const int bn = blockIdx.x * 128;
    const int wm = (wave >> 1) * 64;
    const int wn = (wave & 1) * 64;
    const int qd = lane >> 4;
    const int md = lane & 15;

    const float* Bm;
    int bnb;
    if (bn >= split2)      { Bm = B2; bnb = bn - split2; }
    else if (bn >= split1) { Bm = B1; bnb = bn - split1; }
    else                   { Bm = B0; bnb = bn; }

    f32x4 acc[4][4] = {};

    for (int k0 = 0; k0 < K; k0 += 32) {
        f16x8 ra[2], rb[2];
        #pragma unroll
        for (int c = 0; c < 2; ++c) {
            const int e   = c * 256 + tid;
            const int row = e >> 2;
            const int col = (e & 3) * 8;
            if (A_F16) {
                ra[c] = *(const f16x8*)((const _Float16*)Av + (size_t)(bm + row) * K + k0 + col);
            } else {
                const float* ap = (const float*)Av + (size_t)(bm + row) * K + k0 + col;
                float4 f0 = *(const float4*)ap;
                float4 f1 = *(const float4*)(ap + 4);
                ra[c][0] = (_Float16)f0.x; ra[c][1] = (_Float16)f0.y;
                ra[c][2] = (_Float16)f0.z; ra[c][3] = (_Float16)f0.w;
                ra[c][4] = (_Float16)f1.x; ra[c][5] = (_Float16)f1.y;
                ra[c][6] = (_Float16)f1.z; ra[c][7] = (_Float16)f1.w;
            }
            {
                const float* bp = Bm + (size_t)(bnb + row) * K + k0 + col;
                float4 f0 = *(const float4*)bp;
                float4 f1 = *(const float4*)(bp + 4);
                rb[c][0] = (_Float16)f0.x; rb[c][1] = (_Float16)f0.y;
                rb[c][2] = (_Float16)f0.z; rb[c][3] = (_Float16)f0.w;
                rb[c][4] = (_Float16)f1.x; rb[c][5] = (_Float16)f1.y;
                rb[c][6] = (_Float16)f1.z; rb[c][7] = (_Float16)f1.w;
            }
        }
        __syncthreads();
        #pragma unroll
        for (int c = 0; c < 2; ++c) {
            const int e   = c * 256 + tid;
            const int row = e >> 2;
            const int col = (e & 3) * 8;
            *(f16x8*)(&As[row * 40 + col]) = ra[c];
            *(f16x8*)(&Bs[row * 40 + col]) = rb[c];
        }
        __syncthreads();

        f16x8 af[4], bg[4];
        #pragma unroll
        for (int i = 0; i < 4; ++i) {
            af[i] = *(const f16x8*)(&As[(wm + i * 16 + md) * 40 + qd * 8]);
            bg[i] = *(const f16x8*)(&Bs[(wn + i * 16 + md) * 40 + qd * 8]);
        }
        #pragma unroll
        for (int i = 0; i < 4; ++i) {
            #pragma unroll
            for (int j = 0; j < 4; ++j) {
                acc[i][j] = __builtin_amdgcn_mfma_f32_16x16x32_f16(af[i], bg[j], acc[i][j], 0, 0, 0);
            }
        }
    }

    #pragma unroll
    for (int i = 0; i < 4; ++i) {
        #pragma unroll
        for (int j = 0; j < 4; ++j) {
            #pragma unroll
            for (int r = 0; r < 4; ++r) {
                const int row = bm + wm + i * 16 + qd * 4 + r;
                const int col = bn + wn + j * 16 + md;
                if (OUT_F32) ((float*)Cv)[(size_t)row * ldc + col] = acc[i][j][r];
                else ((_Float16*)Cv)[(size_t)row * ldc + col] = (_Float16)acc[i][j][r];
            }
        }
    }
}

// Fused post-GEMM normalization: blocks [0, QKB) do RMSNorm+RoPE for q/k
// head-vectors; blocks [QKB, QKB+256) do RMSNorm+transpose for v.
#define QKB ((T_TOK * 24) / 4)
__global__ __launch_bounds__(256)
void norm_all(const _Float16* __restrict__ qkv,   // T x 4096 (fp16)
              const float* __restrict__ cosp,     // T x 128 (fp32)
              const float* __restrict__ sinp,
              const float* __restrict__ qnw,
              const float* __restrict__ knw,
              _Float16* __restrict__ qo,          // T x 16 x 128
              _Float16* __restrict__ ko,          // T x 8 x 128
              _Float16* __restrict__ vt)          // KV x 128 x T
{
    __shared__ _Float16 tile[128 * 72];
    const int tid = threadIdx.x;

    if (blockIdx.x < QKB) {
        const unsigned idx  = blockIdx.x * 4 + (tid >> 6);
        const int lane = tid & 63;
        const int t = idx / 24;
        const int r = idx - t * 24;

        const size_t base = (size_t)t * 4096 + r * 128;
        float x0 = (float)qkv[base + lane];
        float x1 = (float)qkv[base + lane + 64];

        float ss = x0 * x0 + x1 * x1;
        #pragma unroll
        for (int s = 32; s; s >>= 1) ss += __shfl_xor(ss, s, 64);
        const float inv = rsqrtf(ss * (1.0f / 128.0f) + 1e-6f);
        float y0 = x0 * inv, y1 = x1 * inv;

        if (r < 16) { y0 *= qnw[lane]; y1 *= qnw[lane + 64]; }
        else        { y0 *= knw[lane]; y1 *= knw[lane + 64]; }

        const float c0 = cosp[t * 128 + lane];
        const float s0 = sinp[t * 128 + lane];
        const float c1 = cosp[t * 128 + lane + 64];
        const float s1 = sinp[t * 128 + lane + 64];
        const float o0 = y0 * c0 - y1 * s0;
        const float o1 = y1 * c1 + y0 * s1;

        const _Float16 b0 = (_Float16)o0, b1 = (_Float16)o1;
        if (r < 16) { _Float16* p = qo + ((size_t)t * NH  + r)        * HD; p[lane] = b0; p[lane + 64] = b1; }
        else        { _Float16* p = ko + ((size_t)t * NKV + (r - 16)) * HD; p[lane] = b0; p[lane + 64] = b1; }
    } else {
        const int bv  = blockIdx.x - QKB;
        const int t0  = (bv & 31) * 64;
        const int kvh = bv >> 5;
        const int tok = tid >> 2;
        const int part = tid & 3;

        const _Float16* vp = qkv + (size_t)(t0 + tok) * 4096 + 3072 + kvh * 128 + part * 32;
        f16x8 raw[4];
        float x[32];
        float ss = 0.f;
        #pragma unroll
        for (int b = 0; b < 4; ++b) {
            raw[b] = *(const f16x8*)(vp + b * 8);
            #pragma unroll
            for (int j = 0; j < 8; ++j) { x[b*8+j] = (float)raw[b][j]; ss += x[b*8+j] * x[b*8+j]; }
        }
        ss += __shfl_xor(ss, 1, 64);
        ss += __shfl_xor(ss, 2, 64);
        const float inv = rsqrtf(ss * (1.0f / 128.0f) + 1e-6f);
        #pragma unroll
        for (int j = 0; j < 32; ++j) tile[(part * 32 + j) * 72 + tok] = (_Float16)(x[j] * inv);
        __syncthreads();

        const int d = tid >> 1, half = tid & 1;
        _Float16* op = vt + ((size_t)kvh * HD + d) * T_TOK + t0 + half * 32;
        #pragma unroll
        for (int j = 0; j < 4; ++j)
            *(f16x8*)(op + j * 8) = *(const f16x8*)(&tile[d * 72 + half * 32 + j * 8]);
    }
}

// MFMA sliding-window GQA flash attention (unchanged).
__global__ __launch_bounds__(256)
void attn_mfma(const _Float16* __restrict__ q,   // T x 16 x 128
               const _Float16* __restrict__ k,   // T x 8 x 128
               const _Float16* __restrict__ vt,  // KV x 128 x T
               const int* __restrict__ cu,
               _Float16* __restrict__ attn)      // T x (16*128)
{
    __shared__ __align__(16) _Float16 Ks[64 * 136];
    __shared__ __align__(16) _Float16 Vs[128 * 72];
    __shared__ __align__(16) _Float16 Ps[64 * 72];

    const int h   = blockIdx.y;
    const int kvh = h >> 1;
    const int t0  = blockIdx.x * 64;
    const int tid = threadIdx.x;
    const int w   = tid >> 6;
    const int lane = tid & 63;
    const int qd  = lane >> 4;
    const int md  = lane & 15;

    int seg_lo = (t0 >= cu[1]) ? cu[1] : cu[0];

    f16x8 qf[4];
    {
        const _Float16* qp = q + ((size_t)(t0 + w * 16 + md) * NH + h) * HD;
        #pragma unroll
        for (int ks = 0; ks < 4; ++ks) qf[ks] = *(const f16x8*)(qp + ks * 32 + qd * 8);
    }

    f32x4 O[8] = {};
    float mR[4], lR[4];
    #pragma unroll
    for (int r = 0; r < 4; ++r) { mR[r] = -1e30f; lR[r] = 0.f; }

    int blk_lo = t0 - (SW - 1); if (blk_lo < seg_lo) blk_lo = seg_lo;
    const int c_lo = blk_lo & ~63;

    for (int cs = c_lo; cs <= t0 + 63; cs += 64) {
        __syncthreads();
        #pragma unroll
        for (int g = 0; g < 4; ++g) {
            const int e = g * 256 + tid;
            const int key = e >> 4, d0 = (e & 15) * 8;
            *(f16x8*)(&Ks[key * 136 + d0]) =
                *(const f16x8*)(k + ((size_t)(cs + key) * NKV + kvh) * HD + d0);
        }
        #pragma unroll
        for (int g = 0; g < 4; ++g) {
            const int e = g * 256 + tid;
            const int d = e >> 3, c0 = (e & 7) * 8;
            *(f16x8*)(&Vs[d * 72 + c0]) =
                *(const f16x8*)(vt + ((size_t)kvh * HD + d) * T_TOK + cs + c0);
        }
        __syncthreads();

        f32x4 S[4] = {};
        #pragma unroll
        for (int nt = 0; nt < 4; ++nt) {
            #pragma unroll
            for (int ks = 0; ks < 4; ++ks) {
                f16x8 kf = *(const f16x8*)(&Ks[(nt * 16 + md) * 136 + ks * 32 + qd * 8]);
                S[nt] = __builtin_amdgcn_mfma_f32_16x16x32_f16(qf[ks], kf, S[nt], 0, 0, 0);
            }
        }

        const int rowb = t0 + w * 16 + qd * 4;
        float alpha[4];
        #pragma unroll
        for (int r = 0; r < 4; ++r) {
            const int rt = rowb + r;
            float mx = -1e30f;
            #pragma unroll
            for (int nt = 0; nt < 4; ++nt) {
                const int col = cs + nt * 16 + md;
                const bool ok = (col <= rt) && (col + (SW - 1) >= rt);
                const float s = ok ? S[nt][r] : -1e30f;
                S[nt][r] = s;
                mx = fmaxf(mx, s);
            }
            mx = fmaxf(mx, __shfl_xor(mx, 1, 64));
            mx = fmaxf(mx, __shfl_xor(mx, 2, 64));
            mx = fmaxf(mx, __shfl_xor(mx, 4, 64));
            mx = fmaxf(mx, __shfl_xor(mx, 8, 64));
            const float mn = fmaxf(mR[r], mx);
            alpha[r] = __expf(mR[r] - mn);
            mR[r] = mn;
        }

        #pragma unroll
        for (int r = 0; r < 4; ++r) {
            float rs = 0.f;
            #pragma unroll
            for (int nt = 0; nt < 4; ++nt) {
                const float p = __expf(S[nt][r] - mR[r]);
                S[nt][r] = p;
                rs += p;
            }
            rs += __shfl_xor(rs, 1, 64);
            rs += __shfl_xor(rs, 2, 64);
            rs += __shfl_xor(rs, 4, 64);
            rs += __shfl_xor(rs, 8, 64);
            lR[r] = lR[r] * alpha[r] + rs;
        }
        #pragma unroll
        for (int nt = 0; nt < 4; ++nt) {
            f16x4 p4;
            #pragma unroll
            for (int r = 0; r < 4; ++r) p4[r] = (_Float16)S[nt][r];
            *(f16x4*)(&Ps[(nt * 16 + md) * 72 + w * 16 + qd * 4]) = p4;
        }

        #pragma unroll
        for (int nt = 0; nt < 8; ++nt)
            #pragma unroll
            for (int r = 0; r < 4; ++r) O[nt][r] *= alpha[r];

        #pragma unroll
        for (int ks2 = 0; ks2 < 2; ++ks2) {
            f16x8 pf;
            #pragma unroll
            for (int j = 0; j < 8; ++j)
                pf[j] = Ps[(ks2 * 32 + qd * 8 + j) * 72 + w * 16 + md];
            #pragma unroll
            for (int nt = 0; nt < 8; ++nt) {
                f16x8 vf = *(const f16x8*)(&Vs[(nt * 16 + md) * 72 + ks2 * 32 + qd * 8]);
                O[nt] = __builtin_amdgcn_mfma_f32_16x16x32_f16(pf, vf, O[nt], 0, 0, 0);
            }
        }
    }

    float inv[4];
    #pragma unroll
    for (int r = 0; r < 4; ++r) inv[r] = 1.0f / lR[r];
    __syncthreads();
    #pragma unroll
    for (int nt = 0; nt < 8; ++nt)
        #pragma unroll
        for (int r = 0; r < 4; ++r)
            Ks[(w * 16 + qd * 4 + r) * 136 + nt * 16 + md] = (_Float16)(O[nt][r] * inv[r]);
    __syncthreads();
    #pragma unroll
    for (int g = 0; g < 4; ++g) {
        const int e = g * 256 + tid;
        const int row = e >> 4, d0 = (e & 15) * 8;
        *(f16x8*)(attn + ((size_t)(t0 + row) * NH + h) * HD + d0) =
            *(const f16x8*)(&Ks[row * 136 + d0]);
    }
}

extern "C" void kernel_launch(void* const* d_in, const int* in_sizes, int n_in,
                              void* d_out, int out_size, void* d_ws, size_t ws_size,
                              hipStream_t stream)
{
    const float* hs   = (const float*)d_in[0];
    const float* cosp = (const float*)d_in[1];
    const float* sinp = (const float*)d_in[2];
    const float* qw   = (const float*)d_in[3];
    const float* kw   = (const float*)d_in[4];
    const float* vw   = (const float*)d_in[5];
    const float* ow   = (const float*)d_in[6];
    const float* qnw  = (const float*)d_in[7];
    const float* knw  = (const float*)d_in[8];
    const int*   cu   = (const int*)d_in[9];
    float*       out  = (float*)d_out;

    // base workspace (fp16): qkv[T,4096] | q[T,16,128] | k[T,8,128] | vt[KV,128,T]
    _Float16* qkv   = (_Float16*)d_ws;
    _Float16* qb    = qkv  + (size_t)T_TOK * 4096;
    _Float16* kb    = qb   + (size_t)T_TOK * 2048;
    _Float16* vtb   = kb   + (size_t)T_TOK * 1024;
    _Float16* attnb = qkv;   // qkv dead after norm kernels

    // fp16 pre-cast region (needs ~64 MiB total ws)
    _Float16* hs16  = vtb  + (size_t)T_TOK * 1024;
    _Float16* qw16  = hs16 + (size_t)T_TOK * 2048;
    _Float16* kw16  = qw16 + (size_t)2048 * 2048;
    _Float16* vw16  = kw16 + (size_t)1024 * 2048;
    _Float16* ow16  = vw16 + (size_t)1024 * 2048;
    const size_t need = ((size_t)T_TOK * 4096 + T_TOK * 2048 + T_TOK * 1024 + T_TOK * 1024
                       + T_TOK * 2048 + 2048 * 2048 + 1024 * 2048 + 1024 * 2048 + 2048 * 2048)
                       * sizeof(_Float16);
    const bool precast = ws_size >= need;   // ws_size is call-invariant: graph-safe

    const dim3 blk(256);

    if (precast) {
        cast_all<<<8192, blk, 0, stream>>>(hs, qw, kw, vw, ow, hs16, qw16, kw16, vw16, ow16);
        gemm_dma<0><<<dim3(32, 16), blk, 0, stream>>>(hs16, qw16, kw16, vw16, 2048, 3072,
                                                      qkv, 2048, 4096);
    } else {
        gemm_bt<0, 0><<<dim3(32, 16), blk, 0, stream>>>(hs, qw, kw, vw, 2048, 3072,
                                                        qkv, 2048, 4096);
    }
    norm_all<<<dim3(QKB + 256), blk, 0, stream>>>(qkv, cosp, sinp, qnw, knw, qb, kb, vtb);
    attn_mfma<<<dim3(T_TOK / 64, NH), blk, 0, stream>>>(qb, kb, vtb, cu, attnb);
    if (precast) {
        gemm_dma<1><<<dim3(16, 16), blk, 0, stream>>>(attnb, ow16, ow16, ow16, 1 << 30, 1 << 30,
                                                      out, 2048, 2048);
    } else {
        gemm_bt<1, 1><<<dim3(16, 16), blk, 0, stream>>>(attnb, ow, ow, ow, 1 << 30, 1 << 30,
                                                        out, 2048, 2048);
    }
}

// Round 9
// 247.603 us; speedup vs baseline: 2.2253x; 1.0264x over previous
//
#include <hip/hip_runtime.h>
#include <hip/hip_bf16.h>
#include <stdint.h>

#define T_TOK 2048
#define NH 16
#define NKV 8
#define HD 128
#define SW 512

typedef _Float16 f16x8 __attribute__((ext_vector_type(8)));
typedef _Float16 f16x4 __attribute__((ext_vector_type(4)));
typedef float f32x4 __attribute__((ext_vector_type(4)));

#define AS1 __attribute__((address_space(1)))
#define AS3 __attribute__((address_space(3)))

// One kernel casts all five fp32 tensors to fp16 (block-uniform branch).
__global__ __launch_bounds__(256)
void cast_all(const float* __restrict__ hs, const float* __restrict__ qw,
              const float* __restrict__ kw, const float* __restrict__ vw,
              const float* __restrict__ ow,
              _Float16* __restrict__ hs16, _Float16* __restrict__ qw16,
              _Float16* __restrict__ kw16, _Float16* __restrict__ vw16,
              _Float16* __restrict__ ow16)
{
    const int b = blockIdx.x;
    const float* src; _Float16* dst; int base;
    if (b < 2048)      { src = hs; dst = hs16; base = b; }
    else if (b < 4096) { src = qw; dst = qw16; base = b - 2048; }
    else if (b < 5120) { src = kw; dst = kw16; base = b - 4096; }
    else if (b < 6144) { src = vw; dst = vw16; base = b - 5120; }
    else               { src = ow; dst = ow16; base = b - 6144; }
    const int i = (base * 256 + threadIdx.x) * 8;
    float4 f0 = *(const float4*)(src + i);
    float4 f1 = *(const float4*)(src + i + 4);
    f16x8 o;
    o[0] = (_Float16)f0.x; o[1] = (_Float16)f0.y; o[2] = (_Float16)f0.z; o[3] = (_Float16)f0.w;
    o[4] = (_Float16)f1.x; o[5] = (_Float16)f1.y; o[6] = (_Float16)f1.z; o[7] = (_Float16)f1.w;
    *(f16x8*)(dst + i) = o;
}

// Double-buffered DMA GEMM, 64x128 tile (M x N): occupancy-first variant.
// QKV grid 1024 (4 blocks/CU), O-proj 512 (2/CU) — the K-loop is
// latency-stall-bound (MfmaUtil 25 + VALUBusy 14 at 2 blocks/CU), so
// doubling resident waves beats per-block MFMA amortization.
// Per wave/iter: 8 MFMA + 3 global_load_lds(16B). LDS 24 KB dbuf.
template<int OUT_F32>
__global__ __launch_bounds__(256)
void gemm_dma(const _Float16* __restrict__ A,
              const _Float16* __restrict__ B0,
              const _Float16* __restrict__ B1,
              const _Float16* __restrict__ B2,
              int split1, int split2,
              void* __restrict__ Cv,
              int K, int ldc)
{
    __shared__ __align__(16) _Float16 As[2][64 * 32];
    __shared__ __align__(16) _Float16 Bs[2][128 * 32];

    const int tid  = threadIdx.x;
    const int wave = tid >> 6;
    const int lane = tid & 63;
    const int bm = blockIdx.y * 64;
    const int bn = blockIdx.x * 128;
    const int wm = (wave >> 1) * 32;   // 2 m-tiles of 16
    const int wn = (wave & 1) * 64;    // 4 n-tiles of 16
    const int qd = lane >> 4;
    const int md = lane & 15;
    const int srow = lane >> 2;        // staging row within 16-row chunk
    const int scol = (lane & 3) * 8;   // staging col (8 fp16 = 16 B)

    const _Float16* Bm;
    int bnb;
    if (bn >= split2)      { Bm = B2; bnb = bn - split2; }
    else if (bn >= split1) { Bm = B1; bnb = bn - split1; }
    else                   { Bm = B0; bnb = bn; }

    f32x4 acc[2][4] = {};

    // wave stages A rows wave*16..+15 (1 chunk), B rows wave*32..+31 (2 chunks)
    const _Float16* aBase = A  + (size_t)(bm  + wave * 16 + srow) * K + scol;
    const _Float16* bBase = Bm + (size_t)(bnb + wave * 32 + srow) * K + scol;

    const int nIter = K / 32;
    // prologue: stage tile 0 into buf 0
    __builtin_amdgcn_global_load_lds((const AS1 void*)aBase,
                                     (AS3 void*)(&As[0][wave * 512]), 16, 0, 0);
    #pragma unroll
    for (int c = 0; c < 2; ++c) {
        __builtin_amdgcn_global_load_lds((const AS1 void*)(bBase + (size_t)c * 16 * K),
                                         (AS3 void*)(&Bs[0][(wave * 2 + c) * 512]), 16, 0, 0);
    }
    __syncthreads();

    for (int it = 0; it < nIter; ++it) {
        const int buf = it & 1;
        if (it + 1 < nIter) {
            const int k1 = (it + 1) * 32;
            __builtin_amdgcn_global_load_lds((const AS1 void*)(aBase + k1),
                                             (AS3 void*)(&As[buf ^ 1][wave * 512]), 16, 0, 0);
            #pragma unroll
            for (int c = 0; c < 2; ++c) {
                __builtin_amdgcn_global_load_lds((const AS1 void*)(bBase + (size_t)c * 16 * K + k1),
                                                 (AS3 void*)(&Bs[buf ^ 1][(wave * 2 + c) * 512]), 16, 0, 0);
            }
        }

        f16x8 af[2], bg[4];
        #pragma unroll
        for (int i = 0; i < 2; ++i)
            af[i] = *(const f16x8*)(&As[buf][(wm + i * 16 + md) * 32 + qd * 8]);
        #pragma unroll
        for (int j = 0; j < 4; ++j)
            bg[j] = *(const f16x8*)(&Bs[buf][(wn + j * 16 + md) * 32 + qd * 8]);
        #pragma unroll
        for (int i = 0; i < 2; ++i) {
            #pragma unroll
            for (int j = 0; j < 4; ++j) {
                acc[i][j] = __builtin_amdgcn_mfma_f32_16x16x32_f16(af[i], bg[j], acc[i][j], 0, 0, 0);
            }
        }
        __syncthreads();   // readers done with buf + prefetch drained
    }

    // C/D layout: col = lane&15, row = quad*4 + reg  [verified m89/m91]
    #pragma unroll
    for (int i = 0; i < 2; ++i) {
        #pragma unroll
        for (int j = 0; j < 4; ++j) {
            #pragma unroll
            for (int r = 0; r < 4; ++r) {
                const int row = bm + wm + i * 16 + qd * 4 + r;
                const int col = bn + wn + j * 16 + md;
                if (OUT_F32) ((float*)Cv)[(size_t)row * ldc + col] = acc[i][j][r];
                else ((_Float16*)Cv)[(size_t)row * ldc + col] = (_Float16)acc[i][j][r];
            }
        }
    }
}

// Fallback GEMM (register staging, fp32 operands) for small-ws path only.
template<int A_F16, int OUT_F32>
__global__ __launch_bounds__(256)
void gemm_bt(const void* __restrict__ Av,
             const float* __restrict__ B0,
             const float* __restrict__ B1,
             const float* __restrict__ B2,
             int split1, int split2,
             void* __restrict__ Cv,
             int K, int ldc)
{
    __shared__ __align__(16) _Float16 As[128 * 40];
    __shared__ __align__(16) _Float16 Bs[128 * 40];

    const int tid  = threadIdx.x;
    const int wave = tid >> 6;
    const int lane = tid & 63;
    const int bm = blockIdx.y * 128;
    const int bn = blockIdx.x * 128;
    const int wm = (wave >> 1) * 64;
    const int wn = (wave & 1) * 64;
    const int qd = lane >> 4;
    const int md = lane & 15;

    const float* Bm;
    int bnb;
    if (bn >= split2)      { Bm = B2; bnb = bn - split2; }
    else if (bn >= split1) { Bm = B1; bnb = bn - split1; }
    else                   { Bm = B0; bnb = bn; }

    f32x4 acc[4][4] = {};

    for (int k0 = 0; k0 < K; k0 += 32) {
        f16x8 ra[2], rb[2];
        #pragma unroll
        for (int c = 0; c < 2; ++c) {
            const int e   = c * 256 + tid;
            const int row = e >> 2;
            const int col = (e & 3) * 8;
            if (A_F16) {
                ra[c] = *(const f16x8*)((const _Float16*)Av + (size_t)(bm + row) * K + k0 + col);
            } else {
                const float* ap = (const float*)Av + (size_t)(bm + row) * K + k0 + col;
                float4 f0 = *(const float4*)ap;
                float4 f1 = *(const float4*)(ap + 4);
                ra[c][0] = (_Float16)f0.x; ra[c][1] = (_Float16)f0.y;
                ra[c][2] = (_Float16)f0.z; ra[c][3] = (_Float16)f0.w;
                ra[c][4] = (_Float16)f1.x; ra[c][5] = (_Float16)f1.y;
                ra[c][6] = (_Float16)f1.z; ra[c][7] = (_Float16)f1.w;
            }
            {
                const float* bp = Bm + (size_t)(bnb + row) * K + k0 + col;
                float4 f0 = *(const float4*)bp;
                float4 f1 = *(const float4*)(bp + 4);
                rb[c][0] = (_Float16)f0.x; rb[c][1] = (_Float16)f0.y;
                rb[c][2] = (_Float16)f0.z; rb[c][3] = (_Float16)f0.w;
                rb[c][4] = (_Float16)f1.x; rb[c][5] = (_Float16)f1.y;
                rb[c][6] = (_Float16)f1.z; rb[c][7] = (_Float16)f1.w;
            }
        }
        __syncthreads();
        #pragma unroll
        for (int c = 0; c < 2; ++c) {
            const int e   = c * 256 + tid;
            const int row = e >> 2;
            const int col = (e & 3) * 8;
            *(f16x8*)(&As[row * 40 + col]) = ra[c];
            *(f16x8*)(&Bs[row * 40 + col]) = rb[c];
        }
        __syncthreads();

        f16x8 af[4], bg[4];
        #pragma unroll
        for (int i = 0; i < 4; ++i) {
            af[i] = *(const f16x8*)(&As[(wm + i * 16 + md) * 40 + qd * 8]);
            bg[i] = *(const f16x8*)(&Bs[(wn + i * 16 + md) * 40 + qd * 8]);
        }
        #pragma unroll
        for (int i = 0; i < 4; ++i) {
            #pragma unroll
            for (int j = 0; j < 4; ++j) {
                acc[i][j] = __builtin_amdgcn_mfma_f32_16x16x32_f16(af[i], bg[j], acc[i][j], 0, 0, 0);
            }
        }
    }

    #pragma unroll
    for (int i = 0; i < 4; ++i) {
        #pragma unroll
        for (int j = 0; j < 4; ++j) {
            #pragma unroll
            for (int r = 0; r < 4; ++r) {
                const int row = bm + wm + i * 16 + qd * 4 + r;
                const int col = bn + wn + j * 16 + md;
                if (OUT_F32) ((float*)Cv)[(size_t)row * ldc + col] = acc[i][j][r];
                else ((_Float16*)Cv)[(size_t)row * ldc + col] = (_Float16)acc[i][j][r];
            }
        }
    }
}

// Fused post-GEMM normalization: blocks [0, QKB) do RMSNorm+RoPE for q/k
// head-vectors; blocks [QKB, QKB+256) do RMSNorm+transpose for v.
#define QKB ((T_TOK * 24) / 4)
__global__ __launch_bounds__(256)
void norm_all(const _Float16* __restrict__ qkv,   // T x 4096 (fp16)
              const float* __restrict__ cosp,     // T x 128 (fp32)
              const float* __restrict__ sinp,
              const float* __restrict__ qnw,
              const float* __restrict__ knw,
              _Float16* __restrict__ qo,          // T x 16 x 128
              _Float16* __restrict__ ko,          // T x 8 x 128
              _Float16* __restrict__ vt)          // KV x 128 x T
{
    __shared__ _Float16 tile[128 * 72];
    const int tid = threadIdx.x;

    if (blockIdx.x < QKB) {
        const unsigned idx  = blockIdx.x * 4 + (tid >> 6);
        const int lane = tid & 63;
        const int t = idx / 24;
        const int r = idx - t * 24;

        const size_t base = (size_t)t * 4096 + r * 128;
        float x0 = (float)qkv[base + lane];
        float x1 = (float)qkv[base + lane + 64];

        float ss = x0 * x0 + x1 * x1;
        #pragma unroll
        for (int s = 32; s; s >>= 1) ss += __shfl_xor(ss, s, 64);
        const float inv = rsqrtf(ss * (1.0f / 128.0f) + 1e-6f);
        float y0 = x0 * inv, y1 = x1 * inv;

        if (r < 16) { y0 *= qnw[lane]; y1 *= qnw[lane + 64]; }
        else        { y0 *= knw[lane]; y1 *= knw[lane + 64]; }

        const float c0 = cosp[t * 128 + lane];
        const float s0 = sinp[t * 128 + lane];
        const float c1 = cosp[t * 128 + lane + 64];
        const float s1 = sinp[t * 128 + lane + 64];
        const float o0 = y0 * c0 - y1 * s0;
        const float o1 = y1 * c1 + y0 * s1;

        const _Float16 b0 = (_Float16)o0, b1 = (_Float16)o1;
        if (r < 16) { _Float16* p = qo + ((size_t)t * NH  + r)        * HD; p[lane] = b0; p[lane + 64] = b1; }
        else        { _Float16* p = ko + ((size_t)t * NKV + (r - 16)) * HD; p[lane] = b0; p[lane + 64] = b1; }
    } else {
        const int bv  = blockIdx.x - QKB;
        const int t0  = (bv & 31) * 64;
        const int kvh = bv >> 5;
        const int tok = tid >> 2;
        const int part = tid & 3;

        const _Float16* vp = qkv + (size_t)(t0 + tok) * 4096 + 3072 + kvh * 128 + part * 32;
        f16x8 raw[4];
        float x[32];
        float ss = 0.f;
        #pragma unroll
        for (int b = 0; b < 4; ++b) {
            raw[b] = *(const f16x8*)(vp + b * 8);
            #pragma unroll
            for (int j = 0; j < 8; ++j) { x[b*8+j] = (float)raw[b][j]; ss += x[b*8+j] * x[b*8+j]; }
        }
        ss += __shfl_xor(ss, 1, 64);
        ss += __shfl_xor(ss, 2, 64);
        const float inv = rsqrtf(ss * (1.0f / 128.0f) + 1e-6f);
        #pragma unroll
        for (int j = 0; j < 32; ++j) tile[(part * 32 + j) * 72 + tok] = (_Float16)(x[j] * inv);
        __syncthreads();

        const int d = tid >> 1, half = tid & 1;
        _Float16* op = vt + ((size_t)kvh * HD + d) * T_TOK + t0 + half * 32;
        #pragma unroll
        for (int j = 0; j < 4; ++j)
            *(f16x8*)(op + j * 8) = *(const f16x8*)(&tile[d * 72 + half * 32 + j * 8]);
    }
}

// MFMA sliding-window GQA flash attention (unchanged).
__global__ __launch_bounds__(256)
void attn_mfma(const _Float16* __restrict__ q,   // T x 16 x 128
               const _Float16* __restrict__ k,   // T x 8 x 128
               const _Float16* __restrict__ vt,  // KV x 128 x T
               const int* __restrict__ cu,
               _Float16* __restrict__ attn)      // T x (16*128)
{
    __shared__ __align__(16) _Float16 Ks[64 * 136];
    __shared__ __align__(16) _Float16 Vs[128 * 72];
    __shared__ __align__(16) _Float16 Ps[64 * 72];

    const int h   = blockIdx.y;
    const int kvh = h >> 1;
    const int t0  = blockIdx.x * 64;
    const int tid = threadIdx.x;
    const int w   = tid >> 6;
    const int lane = tid & 63;
    const int qd  = lane >> 4;
    const int md  = lane & 15;

    int seg_lo = (t0 >= cu[1]) ? cu[1] : cu[0];

    f16x8 qf[4];
    {
        const _Float16* qp = q + ((size_t)(t0 + w * 16 + md) * NH + h) * HD;
        #pragma unroll
        for (int ks = 0; ks < 4; ++ks) qf[ks] = *(const f16x8*)(qp + ks * 32 + qd * 8);
    }

    f32x4 O[8] = {};
    float mR[4], lR[4];
    #pragma unroll
    for (int r = 0; r < 4; ++r) { mR[r] = -1e30f; lR[r] = 0.f; }

    int blk_lo = t0 - (SW - 1); if (blk_lo < seg_lo) blk_lo = seg_lo;
    const int c_lo = blk_lo & ~63;

    for (int cs = c_lo; cs <= t0 + 63; cs += 64) {
        __syncthreads();
        #pragma unroll
        for (int g = 0; g < 4; ++g) {
            const int e = g * 256 + tid;
            const int key = e >> 4, d0 = (e & 15) * 8;
            *(f16x8*)(&Ks[key * 136 + d0]) =
                *(const f16x8*)(k + ((size_t)(cs + key) * NKV + kvh) * HD + d0);
        }
        #pragma unroll
        for (int g = 0; g < 4; ++g) {
            const int e = g * 256 + tid;
            const int d = e >> 3, c0 = (e & 7) * 8;
            *(f16x8*)(&Vs[d * 72 + c0]) =
                *(const f16x8*)(vt + ((size_t)kvh * HD + d) * T_TOK + cs + c0);
        }
        __syncthreads();

        f32x4 S[4] = {};
        #pragma unroll
        for (int nt = 0; nt < 4; ++nt) {
            #pragma unroll
            for (int ks = 0; ks < 4; ++ks) {
                f16x8 kf = *(const f16x8*)(&Ks[(nt * 16 + md) * 136 + ks * 32 + qd * 8]);
                S[nt] = __builtin_amdgcn_mfma_f32_16x16x32_f16(qf[ks], kf, S[nt], 0, 0, 0);
            }
        }

        const int rowb = t0 + w * 16 + qd * 4;
        float alpha[4];
        #pragma unroll
        for (int r = 0; r < 4; ++r) {
            const int rt = rowb + r;
            float mx = -1e30f;
            #pragma unroll
            for (int nt = 0; nt < 4; ++nt) {
                const int col = cs + nt * 16 + md;
                const bool ok = (col <= rt) && (col + (SW - 1) >= rt);
                const float s = ok ? S[nt][r] : -1e30f;
                S[nt][r] = s;
                mx = fmaxf(mx, s);
            }
            mx = fmaxf(mx, __shfl_xor(mx, 1, 64));
            mx = fmaxf(mx, __shfl_xor(mx, 2, 64));
            mx = fmaxf(mx, __shfl_xor(mx, 4, 64));
            mx = fmaxf(mx, __shfl_xor(mx, 8, 64));
            const float mn = fmaxf(mR[r], mx);
            alpha[r] = __expf(mR[r] - mn);
            mR[r] = mn;
        }

        #pragma unroll
        for (int r = 0; r < 4; ++r) {
            float rs = 0.f;
            #pragma unroll
            for (int nt = 0; nt < 4; ++nt) {
                const float p = __expf(S[nt][r] - mR[r]);
                S[nt][r] = p;
                rs += p;
            }
            rs += __shfl_xor(rs, 1, 64);
            rs += __shfl_xor(rs, 2, 64);
            rs += __shfl_xor(rs, 4, 64);
            rs += __shfl_xor(rs, 8, 64);
            lR[r] = lR[r] * alpha[r] + rs;
        }
        #pragma unroll
        for (int nt = 0; nt < 4; ++nt) {
            f16x4 p4;
            #pragma unroll
            for (int r = 0; r < 4; ++r) p4[r] = (_Float16)S[nt][r];
            *(f16x4*)(&Ps[(nt * 16 + md) * 72 + w * 16 + qd * 4]) = p4;
        }

        #pragma unroll
        for (int nt = 0; nt < 8; ++nt)
            #pragma unroll
            for (int r = 0; r < 4; ++r) O[nt][r] *= alpha[r];

        #pragma unroll
        for (int ks2 = 0; ks2 < 2; ++ks2) {
            f16x8 pf;
            #pragma unroll
            for (int j = 0; j < 8; ++j)
                pf[j] = Ps[(ks2 * 32 + qd * 8 + j) * 72 + w * 16 + md];
            #pragma unroll
            for (int nt = 0; nt < 8; ++nt) {
                f16x8 vf = *(const f16x8*)(&Vs[(nt * 16 + md) * 72 + ks2 * 32 + qd * 8]);
                O[nt] = __builtin_amdgcn_mfma_f32_16x16x32_f16(pf, vf, O[nt], 0, 0, 0);
            }
        }
    }

    float inv[4];
    #pragma unroll
    for (int r = 0; r < 4; ++r) inv[r] = 1.0f / lR[r];
    __syncthreads();
    #pragma unroll
    for (int nt = 0; nt < 8; ++nt)
        #pragma unroll
        for (int r = 0; r < 4; ++r)
            Ks[(w * 16 + qd * 4 + r) * 136 + nt * 16 + md] = (_Float16)(O[nt][r] * inv[r]);
    __syncthreads();
    #pragma unroll
    for (int g = 0; g < 4; ++g) {
        const int e = g * 256 + tid;
        const int row = e >> 4, d0 = (e & 15) * 8;
        *(f16x8*)(attn + ((size_t)(t0 + row) * NH + h) * HD + d0) =
            *(const f16x8*)(&Ks[row * 136 + d0]);
    }
}

extern "C" void kernel_launch(void* const* d_in, const int* in_sizes, int n_in,
                              void* d_out, int out_size, void* d_ws, size_t ws_size,
                              hipStream_t stream)
{
    const float* hs   = (const float*)d_in[0];
    const float* cosp = (const float*)d_in[1];
    const float* sinp = (const float*)d_in[2];
    const float* qw   = (const float*)d_in[3];
    const float* kw   = (const float*)d_in[4];
    const float* vw   = (const float*)d_in[5];
    const float* ow   = (const float*)d_in[6];
    const float* qnw  = (const float*)d_in[7];
    const float* knw  = (const float*)d_in[8];
    const int*   cu   = (const int*)d_in[9];
    float*       out  = (float*)d_out;

    // base workspace (fp16): qkv[T,4096] | q[T,16,128] | k[T,8,128] | vt[KV,128,T]
    _Float16* qkv   = (_Float16*)d_ws;
    _Float16* qb    = qkv  + (size_t)T_TOK * 4096;
    _Float16* kb    = qb   + (size_t)T_TOK * 2048;
    _Float16* vtb   = kb   + (size_t)T_TOK * 1024;
    _Float16* attnb = qkv;   // qkv dead after norm kernels

    // fp16 pre-cast region (needs ~64 MiB total ws)
    _Float16* hs16  = vtb  + (size_t)T_TOK * 1024;
    _Float16* qw16  = hs16 + (size_t)T_TOK * 2048;
    _Float16* kw16  = qw16 + (size_t)2048 * 2048;
    _Float16* vw16  = kw16 + (size_t)1024 * 2048;
    _Float16* ow16  = vw16 + (size_t)1024 * 2048;
    const size_t need = ((size_t)T_TOK * 4096 + T_TOK * 2048 + T_TOK * 1024 + T_TOK * 1024
                       + T_TOK * 2048 + 2048 * 2048 + 1024 * 2048 + 1024 * 2048 + 2048 * 2048)
                       * sizeof(_Float16);
    const bool precast = ws_size >= need;   // ws_size is call-invariant: graph-safe

    const dim3 blk(256);

    if (precast) {
        cast_all<<<8192, blk, 0, stream>>>(hs, qw, kw, vw, ow, hs16, qw16, kw16, vw16, ow16);
        gemm_dma<0><<<dim3(32, 32), blk, 0, stream>>>(hs16, qw16, kw16, vw16, 2048, 3072,
                                                      qkv, 2048, 4096);
    } else {
        gemm_bt<0, 0><<<dim3(32, 16), blk, 0, stream>>>(hs, qw, kw, vw, 2048, 3072,
                                                        qkv, 2048, 4096);
    }
    norm_all<<<dim3(QKB + 256), blk, 0, stream>>>(qkv, cosp, sinp, qnw, knw, qb, kb, vtb);
    attn_mfma<<<dim3(T_TOK / 64, NH), blk, 0, stream>>>(qb, kb, vtb, cu, attnb);
    if (precast) {
        gemm_dma<1><<<dim3(16, 32), blk, 0, stream>>>(attnb, ow16, ow16, ow16, 1 << 30, 1 << 30,
                                                      out, 2048, 2048);
    } else {
        gemm_bt<1, 1><<<dim3(16, 16), blk, 0, stream>>>(attnb, ow, ow, ow, 1 << 30, 1 << 30,
                                                        out, 2048, 2048);
    }
}

// Round 10
// 244.637 us; speedup vs baseline: 2.2523x; 1.0121x over previous
//
#include <hip/hip_runtime.h>
#include <hip/hip_bf16.h>
#include <stdint.h>

#define T_TOK 2048
#define NH 16
#define NKV 8
#define HD 128
#define SW 512

typedef _Float16 f16x8 __attribute__((ext_vector_type(8)));
typedef _Float16 f16x4 __attribute__((ext_vector_type(4)));
typedef float f32x4 __attribute__((ext_vector_type(4)));

#define AS1 __attribute__((address_space(1)))
#define AS3 __attribute__((address_space(3)))

// Casts hs/qw/kw/vw to fp16 (ow is cast later, fused into norm_all).
// Ranges (2048 elems/block): hs[0,2048) qw[2048,4096) kw[4096,5120) vw[5120,6144).
__global__ __launch_bounds__(256)
void cast4(const float* __restrict__ hs, const float* __restrict__ qw,
           const float* __restrict__ kw, const float* __restrict__ vw,
           _Float16* __restrict__ hs16, _Float16* __restrict__ qw16,
           _Float16* __restrict__ kw16, _Float16* __restrict__ vw16)
{
    const int b = blockIdx.x;
    const float* src; _Float16* dst; int base;
    if (b < 2048)      { src = hs; dst = hs16; base = b; }
    else if (b < 4096) { src = qw; dst = qw16; base = b - 2048; }
    else if (b < 5120) { src = kw; dst = kw16; base = b - 4096; }
    else               { src = vw; dst = vw16; base = b - 5120; }
    const int i = (base * 256 + threadIdx.x) * 8;
    float4 f0 = *(const float4*)(src + i);
    float4 f1 = *(const float4*)(src + i + 4);
    f16x8 o;
    o[0] = (_Float16)f0.x; o[1] = (_Float16)f0.y; o[2] = (_Float16)f0.z; o[3] = (_Float16)f0.w;
    o[4] = (_Float16)f1.x; o[5] = (_Float16)f1.y; o[6] = (_Float16)f1.z; o[7] = (_Float16)f1.w;
    *(f16x8*)(dst + i) = o;
}

// Double-buffered DMA GEMM, 128x128 tile (round-8 config: 54.2 µs QKV —
// measured best; 64x128 at 4 blocks/CU was slower, occupancy wasn't binding).
template<int OUT_F32>
__global__ __launch_bounds__(256)
void gemm_dma128(const _Float16* __restrict__ A,
                 const _Float16* __restrict__ B0,
                 const _Float16* __restrict__ B1,
                 const _Float16* __restrict__ B2,
                 int split1, int split2,
                 void* __restrict__ Cv,
                 int K, int ldc)
{
    __shared__ __align__(16) _Float16 As[2][128 * 32];
    __shared__ __align__(16) _Float16 Bs[2][128 * 32];

    const int tid  = threadIdx.x;
    const int wave = tid >> 6;
    const int lane = tid & 63;
    const int bm = blockIdx.y * 128;
    const int bn = blockIdx.x * 128;
    const int wm = (wave >> 1) * 64;
    const int wn = (wave & 1) * 64;
    const int qd = lane >> 4;
    const int md = lane & 15;
    const int srow = lane >> 2;
    const int scol = (lane & 3) * 8;

    const _Float16* Bm;
    int bnb;
    if (bn >= split2)      { Bm = B2; bnb = bn - split2; }
    else if (bn >= split1) { Bm = B1; bnb = bn - split1; }
    else                   { Bm = B0; bnb = bn; }

    f32x4 acc[4][4] = {};

    const _Float16* aBase = A  + (size_t)(bm  + wave * 32 + srow) * K + scol;
    const _Float16* bBase = Bm + (size_t)(bnb + wave * 32 + srow) * K + scol;

    const int nIter = K / 32;
    #pragma unroll
    for (int c = 0; c < 2; ++c) {
        const int chunk = wave * 2 + c;
        __builtin_amdgcn_global_load_lds((const AS1 void*)(aBase + (size_t)c * 16 * K),
                                         (AS3 void*)(&As[0][chunk * 512]), 16, 0, 0);
        __builtin_amdgcn_global_load_lds((const AS1 void*)(bBase + (size_t)c * 16 * K),
                                         (AS3 void*)(&Bs[0][chunk * 512]), 16, 0, 0);
    }
    __syncthreads();

    for (int it = 0; it < nIter; ++it) {
        const int buf = it & 1;
        if (it + 1 < nIter) {
            const int k1 = (it + 1) * 32;
            #pragma unroll
            for (int c = 0; c < 2; ++c) {
                const int chunk = wave * 2 + c;
                __builtin_amdgcn_global_load_lds((const AS1 void*)(aBase + (size_t)c * 16 * K + k1),
                                                 (AS3 void*)(&As[buf ^ 1][chunk * 512]), 16, 0, 0);
                __builtin_amdgcn_global_load_lds((const AS1 void*)(bBase + (size_t)c * 16 * K + k1),
                                                 (AS3 void*)(&Bs[buf ^ 1][chunk * 512]), 16, 0, 0);
            }
        }

        f16x8 af[4], bg[4];
        #pragma unroll
        for (int i = 0; i < 4; ++i) {
            af[i] = *(const f16x8*)(&As[buf][(wm + i * 16 + md) * 32 + qd * 8]);
            bg[i] = *(const f16x8*)(&Bs[buf][(wn + i * 16 + md) * 32 + qd * 8]);
        }
        #pragma unroll
        for (int i = 0; i < 4; ++i) {
            #pragma unroll
            for (int j = 0; j < 4; ++j) {
                acc[i][j] = __builtin_amdgcn_mfma_f32_16x16x32_f16(af[i], bg[j], acc[i][j], 0, 0, 0);
            }
        }
        __syncthreads();
    }

    #pragma unroll
    for (int i = 0; i < 4; ++i) {
        #pragma unroll
        for (int j = 0; j < 4; ++j) {
            #pragma unroll
            for (int r = 0; r < 4; ++r) {
                const int row = bm + wm + i * 16 + qd * 4 + r;
                const int col = bn + wn + j * 16 + md;
                if (OUT_F32) ((float*)Cv)[(size_t)row * ldc + col] = acc[i][j][r];
                else ((_Float16*)Cv)[(size_t)row * ldc + col] = (_Float16)acc[i][j][r];
            }
        }
    }
}

// Double-buffered DMA GEMM, 64x128 tile: for grid-starved O-proj (512 blocks,
// 2 blocks/CU — measured ~13 µs faster than 128x128's 1 block/CU there).
template<int OUT_F32>
__global__ __launch_bounds__(256)
void gemm_dma64(const _Float16* __restrict__ A,
                const _Float16* __restrict__ B0,
                int split1, int split2,
                void* __restrict__ Cv,
                int K, int ldc)
{
    __shared__ __align__(16) _Float16 As[2][64 * 32];
    __shared__ __align__(16) _Float16 Bs[2][128 * 32];

    const int tid  = threadIdx.x;
    const int wave = tid >> 6;
    const int lane = tid & 63;
    const int bm = blockIdx.y * 64;
    const int bn = blockIdx.x * 128;
    const int wm = (wave >> 1) * 32;
    const int wn = (wave & 1) * 64;
    const int qd = lane >> 4;
    const int md = lane & 15;
    const int srow = lane >> 2;
    const int scol = (lane & 3) * 8;

    const _Float16* Bm = B0;
    const int bnb = bn;

    f32x4 acc[2][4] = {};

    const _Float16* aBase = A  + (size_t)(bm  + wave * 16 + srow) * K + scol;
    const _Float16* bBase = Bm + (size_t)(bnb + wave * 32 + srow) * K + scol;

    const int nIter = K / 32;
    __builtin_amdgcn_global_load_lds((const AS1 void*)aBase,
                                     (AS3 void*)(&As[0][wave * 512]), 16, 0, 0);
    #pragma unroll
    for (int c = 0; c < 2; ++c) {
        __builtin_amdgcn_global_load_lds((const AS1 void*)(bBase + (size_t)c * 16 * K),
                                         (AS3 void*)(&Bs[0][(wave * 2 + c) * 512]), 16, 0, 0);
    }
    __syncthreads();

    for (int it = 0; it < nIter; ++it) {
        const int buf = it & 1;
        if (it + 1 < nIter) {
            const int k1 = (it + 1) * 32;
            __builtin_amdgcn_global_load_lds((const AS1 void*)(aBase + k1),
                                             (AS3 void*)(&As[buf ^ 1][wave * 512]), 16, 0, 0);
            #pragma unroll
            for (int c = 0; c < 2; ++c) {
                __builtin_amdgcn_global_load_lds((const AS1 void*)(bBase + (size_t)c * 16 * K + k1),
                                                 (AS3 void*)(&Bs[buf ^ 1][(wave * 2 + c) * 512]), 16, 0, 0);
            }
        }

        f16x8 af[2], bg[4];
        #pragma unroll
        for (int i = 0; i < 2; ++i)
            af[i] = *(const f16x8*)(&As[buf][(wm + i * 16 + md) * 32 + qd * 8]);
        #pragma unroll
        for (int j = 0; j < 4; ++j)
            bg[j] = *(const f16x8*)(&Bs[buf][(wn + j * 16 + md) * 32 + qd * 8]);
        #pragma unroll
        for (int i = 0; i < 2; ++i) {
            #pragma unroll
            for (int j = 0; j < 4; ++j) {
                acc[i][j] = __builtin_amdgcn_mfma_f32_16x16x32_f16(af[i], bg[j], acc[i][j], 0, 0, 0);
            }
        }
        __syncthreads();
    }

    #pragma unroll
    for (int i = 0; i < 2; ++i) {
        #pragma unroll
        for (int j = 0; j < 4; ++j) {
            #pragma unroll
            for (int r = 0; r < 4; ++r) {
                const int row = bm + wm + i * 16 + qd * 4 + r;
                const int col = bn + wn + j * 16 + md;
                if (OUT_F32) ((float*)Cv)[(size_t)row * ldc + col] = acc[i][j][r];
                else ((_Float16*)Cv)[(size_t)row * ldc + col] = (_Float16)acc[i][j][r];
            }
        }
    }
}

// Fallback GEMM (register staging, fp32 operands) for small-ws path only.
template<int A_F16, int OUT_F32>
__global__ __launch_bounds__(256)
void gemm_bt(const void* __restrict__ Av,
             const float* __restrict__ B0,
             const float* __restrict__ B1,
             const float* __restrict__ B2,
             int split1, int split2,
             void* __restrict__ Cv,
             int K, int ldc)
{
    __shared__ __align__(16) _Float16 As[128 * 40];
    __shared__ __align__(16) _Float16 Bs[128 * 40];

    const int tid  = threadIdx.x;
    const int wave = tid >> 6;
    const int lane = tid & 63;
    const int bm = blockIdx.y * 128;
    const int bn = blockIdx.x * 128;
    const int wm = (wave >> 1) * 64;
    const int wn = (wave & 1) * 64;
    const int qd = lane >> 4;
    const int md = lane & 15;

    const float* Bm;
    int bnb;
    if (bn >= split2)      { Bm = B2; bnb = bn - split2; }
    else if (bn >= split1) { Bm = B1; bnb = bn - split1; }
    else                   { Bm = B0; bnb = bn; }

    f32x4 acc[4][4] = {};

    for (int k0 = 0; k0 < K; k0 += 32) {
        f16x8 ra[2], rb[2];
        #pragma unroll
        for (int c = 0; c < 2; ++c) {
            const int e   = c * 256 + tid;
            const int row = e >> 2;
            const int col = (e & 3) * 8;
            if (A_F16) {
                ra[c] = *(const f16x8*)((const _Float16*)Av + (size_t)(bm + row) * K + k0 + col);
            } else {
                const float* ap = (const float*)Av + (size_t)(bm + row) * K + k0 + col;
                float4 f0 = *(const float4*)ap;
                float4 f1 = *(const float4*)(ap + 4);
                ra[c][0] = (_Float16)f0.x; ra[c][1] = (_Float16)f0.y;
                ra[c][2] = (_Float16)f0.z; ra[c][3] = (_Float16)f0.w;
                ra[c][4] = (_Float16)f1.x; ra[c][5] = (_Float16)f1.y;
                ra[c][6] = (_Float16)f1.z; ra[c][7] = (_Float16)f1.w;
            }
            {
                const float* bp = Bm + (size_t)(bnb + row) * K + k0 + col;
                float4 f0 = *(const float4*)bp;
                float4 f1 = *(const float4*)(bp + 4);
                rb[c][0] = (_Float16)f0.x; rb[c][1] = (_Float16)f0.y;
                rb[c][2] = (_Float16)f0.z; rb[c][3] = (_Float16)f0.w;
                rb[c][4] = (_Float16)f1.x; rb[c][5] = (_Float16)f1.y;
                rb[c][6] = (_Float16)f1.z; rb[c][7] = (_Float16)f1.w;
            }
        }
        __syncthreads();
        #pragma unroll
        for (int c = 0; c < 2; ++c) {
            const int e   = c * 256 + tid;
            const int row = e >> 2;
            const int col = (e & 3) * 8;
            *(f16x8*)(&As[row * 40 + col]) = ra[c];
            *(f16x8*)(&Bs[row * 40 + col]) = rb[c];
        }
        __syncthreads();

        f16x8 af[4], bg[4];
        #pragma unroll
        for (int i = 0; i < 4; ++i) {
            af[i] = *(const f16x8*)(&As[(wm + i * 16 + md) * 40 + qd * 8]);
            bg[i] = *(const f16x8*)(&Bs[(wn + i * 16 + md) * 40 + qd * 8]);
        }
        #pragma unroll
        for (int i = 0; i < 4; ++i) {
            #pragma unroll
            for (int j = 0; j < 4; ++j) {
                acc[i][j] = __builtin_amdgcn_mfma_f32_16x16x32_f16(af[i], bg[j], acc[i][j], 0, 0, 0);
            }
        }
    }

    #pragma unroll
    for (int i = 0; i < 4; ++i) {
        #pragma unroll
        for (int j = 0; j < 4; ++j) {
            #pragma unroll
            for (int r = 0; r < 4; ++r) {
                const int row = bm + wm + i * 16 + qd * 4 + r;
                const int col = bn + wn + j * 16 + md;
                if (OUT_F32) ((float*)Cv)[(size_t)row * ldc + col] = acc[i][j][r];
                else ((_Float16*)Cv)[(size_t)row * ldc + col] = (_Float16)acc[i][j][r];
            }
        }
    }
}

// Fused post-GEMM normalization + ow cast:
// blocks [0, QKB): RMSNorm+RoPE q/k; [QKB, QKB+256): RMSNorm+transpose v;
// [QKB+256, QKB+256+2048): cast ow -> ow16 (needed only by O-proj, which
// runs after this dispatch — saves a standalone cast launch).
#define QKB ((T_TOK * 24) / 4)
__global__ __launch_bounds__(256)
void norm_all(const _Float16* __restrict__ qkv,   // T x 4096 (fp16)
              const float* __restrict__ cosp,     // T x 128 (fp32)
              const float* __restrict__ sinp,
              const float* __restrict__ qnw,
              const float* __restrict__ knw,
              const float* __restrict__ ow,       // 2048 x 2048 fp32
              _Float16* __restrict__ qo,          // T x 16 x 128
              _Float16* __restrict__ ko,          // T x 8 x 128
              _Float16* __restrict__ vt,          // KV x 128 x T
              _Float16* __restrict__ ow16)
{
    __shared__ _Float16 tile[128 * 72];
    const int tid = threadIdx.x;

    if (blockIdx.x < QKB) {
        const unsigned idx  = blockIdx.x * 4 + (tid >> 6);
        const int lane = tid & 63;
        const int t = idx / 24;
        const int r = idx - t * 24;

        const size_t base = (size_t)t * 4096 + r * 128;
        float x0 = (float)qkv[base + lane];
        float x1 = (float)qkv[base + lane + 64];

        float ss = x0 * x0 + x1 * x1;
        #pragma unroll
        for (int s = 32; s; s >>= 1) ss += __shfl_xor(ss, s, 64);
        const float inv = rsqrtf(ss * (1.0f / 128.0f) + 1e-6f);
        float y0 = x0 * inv, y1 = x1 * inv;

        if (r < 16) { y0 *= qnw[lane]; y1 *= qnw[lane + 64]; }
        else        { y0 *= knw[lane]; y1 *= knw[lane + 64]; }

        const float c0 = cosp[t * 128 + lane];
        const float s0 = sinp[t * 128 + lane];
        const float c1 = cosp[t * 128 + lane + 64];
        const float s1 = sinp[t * 128 + lane + 64];
        const float o0 = y0 * c0 - y1 * s0;
        const float o1 = y1 * c1 + y0 * s1;

        const _Float16 b0 = (_Float16)o0, b1 = (_Float16)o1;
        if (r < 16) { _Float16* p = qo + ((size_t)t * NH  + r)        * HD; p[lane] = b0; p[lane + 64] = b1; }
        else        { _Float16* p = ko + ((size_t)t * NKV + (r - 16)) * HD; p[lane] = b0; p[lane + 64] = b1; }
    } else if (blockIdx.x < QKB + 256) {
        const int bv  = blockIdx.x - QKB;
        const int t0  = (bv & 31) * 64;
        const int kvh = bv >> 5;
        const int tok = tid >> 2;
        const int part = tid & 3;

        const _Float16* vp = qkv + (size_t)(t0 + tok) * 4096 + 3072 + kvh * 128 + part * 32;
        f16x8 raw[4];
        float x[32];
        float ss = 0.f;
        #pragma unroll
        for (int b = 0; b < 4; ++b) {
            raw[b] = *(const f16x8*)(vp + b * 8);
            #pragma unroll
            for (int j = 0; j < 8; ++j) { x[b*8+j] = (float)raw[b][j]; ss += x[b*8+j] * x[b*8+j]; }
        }
        ss += __shfl_xor(ss, 1, 64);
        ss += __shfl_xor(ss, 2, 64);
        const float inv = rsqrtf(ss * (1.0f / 128.0f) + 1e-6f);
        #pragma unroll
        for (int j = 0; j < 32; ++j) tile[(part * 32 + j) * 72 + tok] = (_Float16)(x[j] * inv);
        __syncthreads();

        const int d = tid >> 1, half = tid & 1;
        _Float16* op = vt + ((size_t)kvh * HD + d) * T_TOK + t0 + half * 32;
        #pragma unroll
        for (int j = 0; j < 4; ++j)
            *(f16x8*)(op + j * 8) = *(const f16x8*)(&tile[d * 72 + half * 32 + j * 8]);
    } else {
        const int base = blockIdx.x - (QKB + 256);
        const int i = (base * 256 + tid) * 8;
        float4 f0 = *(const float4*)(ow + i);
        float4 f1 = *(const float4*)(ow + i + 4);
        f16x8 o;
        o[0] = (_Float16)f0.x; o[1] = (_Float16)f0.y; o[2] = (_Float16)f0.z; o[3] = (_Float16)f0.w;
        o[4] = (_Float16)f1.x; o[5] = (_Float16)f1.y; o[6] = (_Float16)f1.z; o[7] = (_Float16)f1.w;
        *(f16x8*)(ow16 + i) = o;
    }
}

// MFMA sliding-window GQA flash attention (unchanged).
__global__ __launch_bounds__(256)
void attn_mfma(const _Float16* __restrict__ q,   // T x 16 x 128
               const _Float16* __restrict__ k,   // T x 8 x 128
               const _Float16* __restrict__ vt,  // KV x 128 x T
               const int* __restrict__ cu,
               _Float16* __restrict__ attn)      // T x (16*128)
{
    __shared__ __align__(16) _Float16 Ks[64 * 136];
    __shared__ __align__(16) _Float16 Vs[128 * 72];
    __shared__ __align__(16) _Float16 Ps[64 * 72];

    const int h   = blockIdx.y;
    const int kvh = h >> 1;
    const int t0  = blockIdx.x * 64;
    const int tid = threadIdx.x;
    const int w   = tid >> 6;
    const int lane = tid & 63;
    const int qd  = lane >> 4;
    const int md  = lane & 15;

    int seg_lo = (t0 >= cu[1]) ? cu[1] : cu[0];

    f16x8 qf[4];
    {
        const _Float16* qp = q + ((size_t)(t0 + w * 16 + md) * NH + h) * HD;
        #pragma unroll
        for (int ks = 0; ks < 4; ++ks) qf[ks] = *(const f16x8*)(qp + ks * 32 + qd * 8);
    }

    f32x4 O[8] = {};
    float mR[4], lR[4];
    #pragma unroll
    for (int r = 0; r < 4; ++r) { mR[r] = -1e30f; lR[r] = 0.f; }

    int blk_lo = t0 - (SW - 1); if (blk_lo < seg_lo) blk_lo = seg_lo;
    const int c_lo = blk_lo & ~63;

    for (int cs = c_lo; cs <= t0 + 63; cs += 64) {
        __syncthreads();
        #pragma unroll
        for (int g = 0; g < 4; ++g) {
            const int e = g * 256 + tid;
            const int key = e >> 4, d0 = (e & 15) * 8;
            *(f16x8*)(&Ks[key * 136 + d0]) =
                *(const f16x8*)(k + ((size_t)(cs + key) * NKV + kvh) * HD + d0);
        }
        #pragma unroll
        for (int g = 0; g < 4; ++g) {
            const int e = g * 256 + tid;
            const int d = e >> 3, c0 = (e & 7) * 8;
            *(f16x8*)(&Vs[d * 72 + c0]) =
                *(const f16x8*)(vt + ((size_t)kvh * HD + d) * T_TOK + cs + c0);
        }
        __syncthreads();

        f32x4 S[4] = {};
        #pragma unroll
        for (int nt = 0; nt < 4; ++nt) {
            #pragma unroll
            for (int ks = 0; ks < 4; ++ks) {
                f16x8 kf = *(const f16x8*)(&Ks[(nt * 16 + md) * 136 + ks * 32 + qd * 8]);
                S[nt] = __builtin_amdgcn_mfma_f32_16x16x32_f16(qf[ks], kf, S[nt], 0, 0, 0);
            }
        }

        const int rowb = t0 + w * 16 + qd * 4;
        float alpha[4];
        #pragma unroll
        for (int r = 0; r < 4; ++r) {
            const int rt = rowb + r;
            float mx = -1e30f;
            #pragma unroll
            for (int nt = 0; nt < 4; ++nt) {
                const int col = cs + nt * 16 + md;
                const bool ok = (col <= rt) && (col + (SW - 1) >= rt);
                const float s = ok ? S[nt][r] : -1e30f;
                S[nt][r] = s;
                mx = fmaxf(mx, s);
            }
            mx = fmaxf(mx, __shfl_xor(mx, 1, 64));
            mx = fmaxf(mx, __shfl_xor(mx, 2, 64));
            mx = fmaxf(mx, __shfl_xor(mx, 4, 64));
            mx = fmaxf(mx, __shfl_xor(mx, 8, 64));
            const float mn = fmaxf(mR[r], mx);
            alpha[r] = __expf(mR[r] - mn);
            mR[r] = mn;
        }

        #pragma unroll
        for (int r = 0; r < 4; ++r) {
            float rs = 0.f;
            #pragma unroll
            for (int nt = 0; nt < 4; ++nt) {
                const float p = __expf(S[nt][r] - mR[r]);
                S[nt][r] = p;
                rs += p;
            }
            rs += __shfl_xor(rs, 1, 64);
            rs += __shfl_xor(rs, 2, 64);
            rs += __shfl_xor(rs, 4, 64);
            rs += __shfl_xor(rs, 8, 64);
            lR[r] = lR[r] * alpha[r] + rs;
        }
        #pragma unroll
        for (int nt = 0; nt < 4; ++nt) {
            f16x4 p4;
            #pragma unroll
            for (int r = 0; r < 4; ++r) p4[r] = (_Float16)S[nt][r];
            *(f16x4*)(&Ps[(nt * 16 + md) * 72 + w * 16 + qd * 4]) = p4;
        }

        #pragma unroll
        for (int nt = 0; nt < 8; ++nt)
            #pragma unroll
            for (int r = 0; r < 4; ++r) O[nt][r] *= alpha[r];

        #pragma unroll
        for (int ks2 = 0; ks2 < 2; ++ks2) {
            f16x8 pf;
            #pragma unroll
            for (int j = 0; j < 8; ++j)
                pf[j] = Ps[(ks2 * 32 + qd * 8 + j) * 72 + w * 16 + md];
            #pragma unroll
            for (int nt = 0; nt < 8; ++nt) {
                f16x8 vf = *(const f16x8*)(&Vs[(nt * 16 + md) * 72 + ks2 * 32 + qd * 8]);
                O[nt] = __builtin_amdgcn_mfma_f32_16x16x32_f16(pf, vf, O[nt], 0, 0, 0);
            }
        }
    }

    float inv[4];
    #pragma unroll
    for (int r = 0; r < 4; ++r) inv[r] = 1.0f / lR[r];
    __syncthreads();
    #pragma unroll
    for (int nt = 0; nt < 8; ++nt)
        #pragma unroll
        for (int r = 0; r < 4; ++r)
            Ks[(w * 16 + qd * 4 + r) * 136 + nt * 16 + md] = (_Float16)(O[nt][r] * inv[r]);
    __syncthreads();
    #pragma unroll
    for (int g = 0; g < 4; ++g) {
        const int e = g * 256 + tid;
        const int row = e >> 4, d0 = (e & 15) * 8;
        *(f16x8*)(attn + ((size_t)(t0 + row) * NH + h) * HD + d0) =
            *(const f16x8*)(&Ks[row * 136 + d0]);
    }
}

extern "C" void kernel_launch(void* const* d_in, const int* in_sizes, int n_in,
                              void* d_out, int out_size, void* d_ws, size_t ws_size,
                              hipStream_t stream)
{
    const float* hs   = (const float*)d_in[0];
    const float* cosp = (const float*)d_in[1];
    const float* sinp = (const float*)d_in[2];
    const float* qw   = (const float*)d_in[3];
    const float* kw   = (const float*)d_in[4];
    const float* vw   = (const float*)d_in[5];
    const float* ow   = (const float*)d_in[6];
    const float* qnw  = (const float*)d_in[7];
    const float* knw  = (const float*)d_in[8];
    const int*   cu   = (const int*)d_in[9];
    float*       out  = (float*)d_out;

    // base workspace (fp16): qkv[T,4096] | q[T,16,128] | k[T,8,128] | vt[KV,128,T]
    _Float16* qkv   = (_Float16*)d_ws;
    _Float16* qb    = qkv  + (size_t)T_TOK * 4096;
    _Float16* kb    = qb   + (size_t)T_TOK * 2048;
    _Float16* vtb   = kb   + (size_t)T_TOK * 1024;
    _Float16* attnb = qkv;   // qkv dead after norm kernels

    // fp16 pre-cast region (needs ~64 MiB total ws)
    _Float16* hs16  = vtb  + (size_t)T_TOK * 1024;
    _Float16* qw16  = hs16 + (size_t)T_TOK * 2048;
    _Float16* kw16  = qw16 + (size_t)2048 * 2048;
    _Float16* vw16  = kw16 + (size_t)1024 * 2048;
    _Float16* ow16  = vw16 + (size_t)1024 * 2048;
    const size_t need = ((size_t)T_TOK * 4096 + T_TOK * 2048 + T_TOK * 1024 + T_TOK * 1024
                       + T_TOK * 2048 + 2048 * 2048 + 1024 * 2048 + 1024 * 2048 + 2048 * 2048)
                       * sizeof(_Float16);
    const bool precast = ws_size >= need;   // ws_size is call-invariant: graph-safe

    const dim3 blk(256);

    if (precast) {
        cast4<<<6144, blk, 0, stream>>>(hs, qw, kw, vw, hs16, qw16, kw16, vw16);
        gemm_dma128<0><<<dim3(32, 16), blk, 0, stream>>>(hs16, qw16, kw16, vw16, 2048, 3072,
                                                         qkv, 2048, 4096);
        norm_all<<<dim3(QKB + 256 + 2048), blk, 0, stream>>>(qkv, cosp, sinp, qnw, knw, ow,
                                                             qb, kb, vtb, ow16);
        attn_mfma<<<dim3(T_TOK / 64, NH), blk, 0, stream>>>(qb, kb, vtb, cu, attnb);
        gemm_dma64<1><<<dim3(16, 32), blk, 0, stream>>>(attnb, ow16, 1 << 30, 1 << 30,
                                                        out, 2048, 2048);
    } else {
        gemm_bt<0, 0><<<dim3(32, 16), blk, 0, stream>>>(hs, qw, kw, vw, 2048, 3072,
                                                        qkv, 2048, 4096);
        norm_all<<<dim3(QKB + 256), blk, 0, stream>>>(qkv, cosp, sinp, qnw, knw, ow,
                                                      qb, kb, vtb, (_Float16*)qkv /*unused*/);
        attn_mfma<<<dim3(T_TOK / 64, NH), blk, 0, stream>>>(qb, kb, vtb, cu, attnb);
        gemm_bt<1, 1><<<dim3(16, 16), blk, 0, stream>>>(attnb, ow, ow, ow, 1 << 30, 1 << 30,
                                                        out, 2048, 2048);
    }
}